// Round 10
// baseline (243.435 us; speedup 1.0000x reference)
//
#include <hip/hip_runtime.h>
#include <hip/hip_bf16.h>

// Attention: out = softmax_causal((xWq+bq)(xWk+bk)^T / sqrt(D)) (xWv+bv) Wo + bo
// B=4, S=2048, D=1024.  All GEMMs bf16 MFMA 16x16x32, fp32 accumulate.
// R10: (1) staging order A-h0(PH0) / all-B(PH1) / A-h1(PH2) so every load has
//      >=2 phases of latency cover before its guarding vmcnt (same counts,
//      same proof shape).  (2) PV split into 3 K-chunks at 768 boundaries:
//      240 live blocks (one round), max NT=12; bf16 partial planes + 3-way
//      merge for rows >= 768, direct write for rows < 768.

typedef __bf16 bf16x8 __attribute__((ext_vector_type(8)));
typedef __bf16 bf16x4 __attribute__((ext_vector_type(4)));
typedef float  f32x4  __attribute__((ext_vector_type(4)));

#define BDIM 1024
#define SDIM 2048
#define BATCH 4

#define BAR()  do { asm volatile("" ::: "memory"); __builtin_amdgcn_s_barrier(); \
                    asm volatile("" ::: "memory"); } while (0)
#define SCB()  __builtin_amdgcn_sched_barrier(0)
#define LGKM0() asm volatile("s_waitcnt lgkmcnt(0)" ::: "memory")

__device__ __forceinline__ void gload_lds16(const void* g, void* l) {
    __builtin_amdgcn_global_load_lds(
        (const __attribute__((address_space(1))) void*)g,
        (__attribute__((address_space(3))) void*)l, 16, 0, 0);
}

// ---------------- fp32 -> bf16 elementwise ----------------
__global__ __launch_bounds__(256) void cvt_f32_bf16(const float* __restrict__ in,
                                                    __bf16* __restrict__ out, long n) {
    long i = ((long)blockIdx.x * 256 + threadIdx.x) * 4;
    if (i + 3 < n) {
        float4 v = *(const float4*)(in + i);
        bf16x4 o;
        o[0] = (__bf16)v.x; o[1] = (__bf16)v.y; o[2] = (__bf16)v.z; o[3] = (__bf16)v.w;
        *(bf16x4*)(out + i) = o;
    }
}

// ---------------- bias concat [bq|bk|bv] -> bcat[3072] ----------------
__global__ __launch_bounds__(256) void concat3(const float* __restrict__ a,
                                               const float* __restrict__ b,
                                               const float* __restrict__ c,
                                               float* __restrict__ o) {
    int i = blockIdx.x * 256 + threadIdx.x;
    if (i < 3072)
        o[i] = (i < 1024) ? a[i] : ((i < 2048) ? b[i - 1024] : c[i - 2048]);
}

// ---------------- transpose (fp32 or bf16 in) -> bf16 out ----------------
template <typename Tin>
__global__ __launch_bounds__(256) void transpose_to_bf16(const Tin* __restrict__ in,
                                                         __bf16* __restrict__ out,
                                                         int ldIn, int ldOut,
                                                         long sIn, long sOut) {
    __shared__ float tile[32][33];
    const long b = blockIdx.z;
    in += b * sIn; out += b * sOut;
    const int r0 = blockIdx.y * 32, c0 = blockIdx.x * 32;
    const int tx = threadIdx.x, ty = threadIdx.y;  // block (32,8)
    #pragma unroll
    for (int j = ty; j < 32; j += 8)
        tile[j][tx] = (float)in[(long)(r0 + j) * ldIn + (c0 + tx)];
    __syncthreads();
    #pragma unroll
    for (int j = ty; j < 32; j += 8)
        out[(long)(c0 + j) * ldOut + (r0 + tx)] = (__bf16)tile[tx][j];
}

// ---------- 256 x BN BT GEMM, BK=64, balanced 4-phase (R8 schedule) ----------
// 8 waves (2M x 4N).  Per-wave output 128 x BN/4: acc[8][NF], NF = BN/64.
//   acc[m][n]   (m=0..3): rows wm*64 + m*16        (A staging half 0)
//   acc[4+m][n] (m=0..3): rows 128 + wm*64 + m*16  (A staging half 1)
// Stage order (R10): A-h0(PH0), all B(PH1), A-h1(PH2), none(PH3).
// Guards: PH3-end vmcnt(2) -> A-h0 (4 phases old) + B (3 phases) landed,
// A-h1 (1.5 phases) keeps flying; PH0-end vmcnt(2) -> A-h1 landed (2.5
// phases after issue).  vmcnt never 0 mid-loop; staging buffer != read
// buffer -> no lgkm drain needed.
// PVMODE: bz = batch*3 + chunk; K-range = [chunk*768, min((by+1)*256,+768));
//         output: chunk0/by<3 -> direct bf16 Cd; chunk0/by>=3 -> bf16 C0;
//         chunk1 -> bf16 plane P1 (rows-768); chunk2 -> P2 (rows-1536).
template <typename Tout, int BN, bool CSKIP, bool PVMODE, bool SWZ>
__global__ __launch_bounds__(512, 2) void gemm4p(const __bf16* __restrict__ Ag,
                                                 const __bf16* __restrict__ Bg,
                                                 Tout* __restrict__ C0,
                                                 __bf16* __restrict__ P1,
                                                 __bf16* __restrict__ P2,
                                                 __bf16* __restrict__ Cd,
                                                 const float* __restrict__ bias,
                                                 int K, int lda, int ldb, int ldc,
                                                 int nbx, long sA, long sB, long sC) {
    constexpr int NF = BN / 64;        // B fragments per wave / B stage chunks
    constexpr int NB = BN / 64;
    int bx, by;
    const int bz = blockIdx.z;
    if (SWZ) {  // XCD-aware contiguous chunks (grid.x % 8 == 0)
        const int flat = blockIdx.x;
        const int w = (flat & 7) * ((int)gridDim.x >> 3) + (flat >> 3);
        bx = w % nbx; by = w / nbx;
    } else { bx = blockIdx.x; by = blockIdx.y; }
    if (CSKIP && bx * BN > by * 256 + 255) return;  // fully above causal diag

    const int m0 = by * 256, n0 = bx * BN;
    int kStart = 0, kEnd = K;
    const __bf16* A; const __bf16* B;
    Tout* C = nullptr;
    __bf16* Wout = nullptr;
    int rShift = 0;
    if (PVMODE) {
        const int b = bz / 3, c = bz - b * 3;
        kStart = c * 768;
        kEnd = min((by + 1) * 256, kStart + 768);
        if (kEnd <= kStart) return;
        A = Ag + (long)b * sA;
        B = Bg + (long)b * sB;
        if (c == 0)      { rShift = 0;    Wout = (by < 3 ? Cd : (__bf16*)C0) + (long)b * sC; }
        else if (c == 1) { rShift = 768;  Wout = P1 + (long)b * 1310720; }   // [1280][1024]
        else             { rShift = 1536; Wout = P2 + (long)b * 524288; }    // [512][1024]
    } else {
        A = Ag + (long)bz * sA;
        B = Bg + (long)bz * sB;
        C = C0 + (long)bz * sC;
    }
    const int NT = (kEnd - kStart) >> 6;   // BK=64 tiles (>= 4 always)

    __shared__ __align__(16) __bf16 As[2][16384];    // [256 rows][64 k], swz
    __shared__ __align__(16) __bf16 Bs[2][BN * 64];  // [BN rows][64 k], swz

    const int tid = threadIdx.x;
    const int wid = tid >> 6, l = tid & 63;
    const int wm = wid >> 2, wn = wid & 3;          // wave grid 2(M) x 4(N)
    const int lr = l & 15, lu = l >> 4;

    // ---- staging source offsets (inverse-swizzled global cols, rule #21) ----
    int srcA[4], srcB[NB];
    #pragma unroll
    for (int i = 0; i < 4; ++i) {
        const int beta = i * 8192 + tid * 16;          // linear LDS byte
        const int r = beta >> 7;                       // row (128B rows)
        const int cb = (beta & 127) ^ ((r & 7) << 4);  // unswizzled col byte
        srcA[i] = (m0 + r) * lda + (cb >> 1);
    }
    #pragma unroll
    for (int i = 0; i < NB; ++i) {
        const int beta = i * 8192 + tid * 16;
        const int r = beta >> 7;
        const int cb = (beta & 127) ^ ((r & 7) << 4);
        srcB[i] = (n0 + r) * ldb + (cb >> 1);
    }
    auto stA = [&](int buf, int half, int koff) {   // 2 gloads = one A half
        #pragma unroll
        for (int i = 0; i < 2; ++i)
            gload_lds16(A + srcA[half * 2 + i] + koff,
                        (char*)&As[buf][0] + (half * 2 + i) * 8192 + wid * 1024);
    };
    auto stB = [&](int buf, int j, int koff) {      // 1 gload = one B chunk
        gload_lds16(B + srcB[j] + koff,
                    (char*)&Bs[buf][0] + j * 8192 + wid * 1024);
    };

    // ---- swizzled fragment read offsets (elements), lane constants ----
    const int xo  = (lr & 7) << 4;                       // row-derived XOR
    const int c0e = ((lu << 4) ^ xo) >> 1;               // kk=0 col elems
    const int c1e = ((64 + (lu << 4)) ^ xo) >> 1;        // kk=1 col elems
    const int aLo = (wm * 64 + lr) * 64;                 // A half-0 strip base
    const int aHi = (128 + wm * 64 + lr) * 64;           // A half-1 strip base
    const int bBase = (wn * (BN / 4) + lr) * 64;

    f32x4 acc[8][NF] = {};
    bf16x8 aR[4], bR[NF];

    // ---- prologue: stage tile 0 in guard order; A-h1 may stay in flight ----
    stA(0, 0, kStart);
    #pragma unroll
    for (int j = 0; j < NB; ++j) stB(0, j, kStart);
    stA(0, 1, kStart);
    asm volatile("s_waitcnt vmcnt(2)" ::: "memory");
    BAR();

    for (int T = 0; T < NT; ++T) {
        const int c = T & 1;
        const bool more = (T + 1 < NT);
        const int k1 = kStart + (T + 1) * 64;
        const __bf16* Ab = &As[c][0];
        const __bf16* Bb = &Bs[c][0];

        // ---- PH0: read A-h0 kk0 (4) + B kk0 (NF) | stage A-h0(T+1) ----
        #pragma unroll
        for (int m = 0; m < 4; ++m) aR[m] = *(const bf16x8*)(Ab + aLo + m * 1024 + c0e);
        #pragma unroll
        for (int n = 0; n < NF; ++n) bR[n] = *(const bf16x8*)(Bb + bBase + n * 1024 + c0e);
        if (more) stA(c ^ 1, 0, k1);
        BAR();
        LGKM0(); SCB();
        __builtin_amdgcn_s_setprio(1);
        #pragma unroll
        for (int m = 0; m < 4; ++m)
            #pragma unroll
            for (int n = 0; n < NF; ++n)
                acc[m][n] = __builtin_amdgcn_mfma_f32_16x16x32_bf16(aR[m], bR[n],
                                                                    acc[m][n], 0, 0, 0);
        __builtin_amdgcn_s_setprio(0);
        if (more) asm volatile("s_waitcnt vmcnt(2)" ::: "memory");  // A-h1(T) landed
        else      asm volatile("s_waitcnt vmcnt(0)" ::: "memory");
        BAR();

        // ---- PH1: read A-h1 kk0 (4) | stage ALL B(T+1) ----
        #pragma unroll
        for (int m = 0; m < 4; ++m) aR[m] = *(const bf16x8*)(Ab + aHi + m * 1024 + c0e);
        if (more) {
            #pragma unroll
            for (int j = 0; j < NB; ++j) stB(c ^ 1, j, k1);
        }
        BAR();
        LGKM0(); SCB();
        __builtin_amdgcn_s_setprio(1);
        #pragma unroll
        for (int m = 0; m < 4; ++m)
            #pragma unroll
            for (int n = 0; n < NF; ++n)
                acc[4 + m][n] = __builtin_amdgcn_mfma_f32_16x16x32_bf16(aR[m], bR[n],
                                                                        acc[4 + m][n], 0, 0, 0);
        __builtin_amdgcn_s_setprio(0);
        BAR();

        // ---- PH2: read A-h0 kk1 (4) + B kk1 (NF) | stage A-h1(T+1) ----
        #pragma unroll
        for (int m = 0; m < 4; ++m) aR[m] = *(const bf16x8*)(Ab + aLo + m * 1024 + c1e);
        #pragma unroll
        for (int n = 0; n < NF; ++n) bR[n] = *(const bf16x8*)(Bb + bBase + n * 1024 + c1e);
        if (more) stA(c ^ 1, 1, k1);
        BAR();
        LGKM0(); SCB();
        __builtin_amdgcn_s_setprio(1);
        #pragma unroll
        for (int m = 0; m < 4; ++m)
            #pragma unroll
            for (int n = 0; n < NF; ++n)
                acc[m][n] = __builtin_amdgcn_mfma_f32_16x16x32_bf16(aR[m], bR[n],
                                                                    acc[m][n], 0, 0, 0);
        __builtin_amdgcn_s_setprio(0);
        BAR();

        // ---- PH3: read A-h1 kk1 (4) | no staging ----
        #pragma unroll
        for (int m = 0; m < 4; ++m) aR[m] = *(const bf16x8*)(Ab + aHi + m * 1024 + c1e);
        BAR();
        LGKM0(); SCB();
        __builtin_amdgcn_s_setprio(1);
        #pragma unroll
        for (int m = 0; m < 4; ++m)
            #pragma unroll
            for (int n = 0; n < NF; ++n)
                acc[4 + m][n] = __builtin_amdgcn_mfma_f32_16x16x32_bf16(aR[m], bR[n],
                                                                        acc[4 + m][n], 0, 0, 0);
        __builtin_amdgcn_s_setprio(0);
        if (more) {  // A-h0 (4 phases) + B (3 phases) landed; A-h1 flies
            asm volatile("s_waitcnt vmcnt(2)" ::: "memory");
            BAR();
        }
    }

    // epilogue: C/D layout col = lane&15, row = (lane>>4)*4 + reg [m89-verified]
    const int rb = (l >> 4) * 4, cl = l & 15;
    #pragma unroll
    for (int n = 0; n < NF; ++n) {
        const int col = n0 + wn * (BN / 4) + n * 16 + cl;
        const float bvv = bias ? bias[col] : 0.f;
        #pragma unroll
        for (int mi = 0; mi < 8; ++mi) {
            const int row = m0 + (mi >> 2) * 128 + wm * 64 + (mi & 3) * 16 + rb;
            #pragma unroll
            for (int r = 0; r < 4; ++r) {
                const float v = acc[mi][n][r] + bvv;
                if constexpr (PVMODE)
                    Wout[(long)(row + r - rShift) * ldc + col] = (__bf16)v;
                else
                    C[(long)(row + r) * ldc + col] = (Tout)v;
            }
        }
    }
}

// ------ merge PV partials (rows 768..2047): ctxb = bf16(m16 + e1 + e2?) ------
__global__ __launch_bounds__(256) void merge3(const __bf16* __restrict__ m16,
                                              const __bf16* __restrict__ e1,
                                              const __bf16* __restrict__ e2,
                                              __bf16* __restrict__ out) {
    const long i = ((long)blockIdx.x * 256 + threadIdx.x) * 8;  // [0, B*1280*1024)
    const long b = i / 1310720;
    const long j = i - b * 1310720;
    const long row = 768 + (j >> 10);
    const long gi = b * 2097152 + 786432 + j;
    const bf16x8 vm = *(const bf16x8*)(m16 + gi);
    const bf16x8 v1 = *(const bf16x8*)(e1 + b * 1310720 + j);
    float s[8];
    #pragma unroll
    for (int t = 0; t < 8; ++t) s[t] = (float)vm[t] + (float)v1[t];
    if (row >= 1536) {
        const bf16x8 v2 = *(const bf16x8*)(e2 + b * 524288 + (j - 786432));
        #pragma unroll
        for (int t = 0; t < 8; ++t) s[t] += (float)v2[t];
    }
    bf16x8 o;
    #pragma unroll
    for (int t = 0; t < 8; ++t) o[t] = (__bf16)s[t];
    *(bf16x8*)(out + gi) = o;
}

// ---------------- causal softmax row kernel (16B/lane, bounded I/O) ----------
__global__ __launch_bounds__(256) void softmax_causal(const __bf16* __restrict__ scores,
                                                      __bf16* __restrict__ P, float scale) {
    const int q = blockIdx.x;
    const long b = blockIdx.y;
    const __bf16* srow = scores + (b * SDIM + q) * (long)SDIM;
    __bf16* prow = P + (b * SDIM + q) * (long)SDIM;
    const int n = q + 1;
    const int kBound = ((q >> 8) + 1) << 8;    // PV reads P cols < kBound only
    const int tid = threadIdx.x;
    const int k0 = tid * 8;
    __shared__ float red[8];

    float vals[8];
    float mx = -1e30f;
    if (k0 < n) {
        const bf16x8 v = *(const bf16x8*)(srow + k0);
        #pragma unroll
        for (int i = 0; i < 8; ++i) {
            const float s = (k0 + i < n) ? (float)v[i] * scale : -1e30f;
            vals[i] = s;
            mx = fmaxf(mx, s);
        }
    } else {
        #pragma unroll
        for (int i = 0; i < 8; ++i) vals[i] = -1e30f;
    }
    #pragma unroll
    for (int o = 32; o > 0; o >>= 1) mx = fmaxf(mx, __shfl_xor(mx, o));
    if ((tid & 63) == 0) red[tid >> 6] = mx;
    __syncthreads();
    mx = fmaxf(fmaxf(red[0], red[1]), fmaxf(red[2], red[3]));

    float p[8];
    float sum = 0.f;
    #pragma unroll
    for (int i = 0; i < 8; ++i) {
        p[i] = __expf(vals[i] - mx);
        sum += p[i];
    }
    #pragma unroll
    for (int o = 32; o > 0; o >>= 1) sum += __shfl_xor(sum, o);
    if ((tid & 63) == 0) red[4 + (tid >> 6)] = sum;
    __syncthreads();
    sum = red[4] + red[5] + red[6] + red[7];

    if (k0 < kBound) {                     // cols >= kBound never read by PV
        const float inv = 1.f / sum;
        bf16x8 o;
        #pragma unroll
        for (int i = 0; i < 8; ++i)
            o[i] = (__bf16)((k0 + i < n) ? p[i] * inv : 0.f);
        *(bf16x8*)(prow + k0) = o;
    }
}

extern "C" void kernel_launch(void* const* d_in, const int* in_sizes, int n_in,
                              void* d_out, int out_size, void* d_ws, size_t ws_size,
                              hipStream_t stream) {
    const float* x  = (const float*)d_in[0];
    // d_in[1] = mask (tril ones) -- causality enforced by index, unused.
    const float* Wq = (const float*)d_in[2];
    const float* bq = (const float*)d_in[3];
    const float* Wk = (const float*)d_in[4];
    const float* bk = (const float*)d_in[5];
    const float* Wv = (const float*)d_in[6];
    const float* bv = (const float*)d_in[7];
    const float* Wo = (const float*)d_in[8];
    const float* bo = (const float*)d_in[9];
    float* out = (float*)d_out;

    char* ws = (char*)d_ws;
    const long MT = (long)BATCH * SDIM;           // 8192 rows
    const long XE = MT * BDIM;
    __bf16* xb    = (__bf16*)(ws);                // 16 MiB, dead after QKV
    __bf16* Wcat  = (__bf16*)(ws + 16777216);     // 6 MiB, dead after QKV
    __bf16* Wot   = (__bf16*)(ws + 23068672);     // 2 MiB (kept for out-proj)
    float*  bcat  = (float*)(ws + 25165824);      // 12 KiB
    __bf16* QKVb  = (__bf16*)(ws + 25178112);     // 48 MiB (8192 x 3072)
    __bf16* Vtb   = (__bf16*)(ws + 75509760);     // 16 MiB (B x [1024][2048])
    __bf16* Sc    = (__bf16*)(ws + 92286976);     // 32 MiB, dead after softmax
    __bf16* Pb    = (__bf16*)(ws + 25178112);     // alias QKVb[0..32M)
    __bf16* ctxM16= (__bf16*)(ws + 92286976);     // 16 MiB bf16, alias Sc
    __bf16* E1    = (__bf16*)(ws);                // 10.5 MiB bf16, alias xb
    __bf16* E2    = (__bf16*)(ws + 16777216);     // 4.2 MiB bf16, alias Wcat
    __bf16* ctxb  = (__bf16*)(ws + 58732544);     // 16 MiB, alias QKVb[32M..48M)

    const long SD  = (long)SDIM * BDIM;           // 2,097,152
    const long SS  = (long)SDIM * SDIM;           // 4,194,304
    const long SQ3 = (long)SDIM * 3 * BDIM;       // 6,291,456

    cvt_f32_bf16<<<dim3((unsigned)(XE / 4 / 256)), 256, 0, stream>>>(x, xb, XE);
    transpose_to_bf16<float><<<dim3(32, 32, 1), dim3(32, 8), 0, stream>>>(Wq, Wcat,             BDIM, BDIM, 0, 0);
    transpose_to_bf16<float><<<dim3(32, 32, 1), dim3(32, 8), 0, stream>>>(Wk, Wcat + 1024*1024, BDIM, BDIM, 0, 0);
    transpose_to_bf16<float><<<dim3(32, 32, 1), dim3(32, 8), 0, stream>>>(Wv, Wcat + 2048*1024, BDIM, BDIM, 0, 0);
    transpose_to_bf16<float><<<dim3(32, 32, 1), dim3(32, 8), 0, stream>>>(Wo, Wot,              BDIM, BDIM, 0, 0);
    concat3<<<dim3(12), 256, 0, stream>>>(bq, bk, bv, bcat);

    // QKV[8192][3072] = x @ Wcat^T + bcat   (BN=192: 512 blocks = 2 rounds, swz)
    gemm4p<__bf16, 192, false, false, true><<<dim3(512, 1, 1), 512, 0, stream>>>(
        xb, Wcat, QKVb, nullptr, nullptr, nullptr, bcat,
        BDIM, BDIM, BDIM, 3072, 16, 0, 0, 0);
    // V^T per batch: [S,1024] (stride 3072) -> [1024][S]
    transpose_to_bf16<__bf16><<<dim3(32, 64, BATCH), dim3(32, 8), 0, stream>>>(
        QKVb + 2048, Vtb, 3072, SDIM, SQ3, SD);
    // scores = Q @ K^T per batch (causal tile skip; 144 live blocks)
    gemm4p<__bf16, 256, true, false, false><<<dim3(8, 8, BATCH), 512, 0, stream>>>(
        QKVb, QKVb + 1024, Sc, nullptr, nullptr, nullptr, nullptr,
        BDIM, 3072, 3072, SDIM, 8, SQ3, SQ3, SS);
    // causal softmax (scale = 1/32)
    softmax_causal<<<dim3(SDIM, BATCH), 256, 0, stream>>>(Sc, Pb, 0.03125f);
    // ctx = P @ V, K split in 3 chunks at 768 (240 live blocks, max NT=12);
    // bf16 partials: chunk0 -> ctxb (by<3) / ctxM16; chunk1 -> E1; chunk2 -> E2
    gemm4p<__bf16, 256, false, true, false><<<dim3(4, 8, 3 * BATCH), 512, 0, stream>>>(
        Pb, Vtb, ctxM16, E1, E2, ctxb, nullptr,
        SDIM, SDIM, SDIM, BDIM, 4, SS, SD, SD);
    // merge partial planes (rows 768..2047) -> bf16 ctx
    merge3<<<dim3((unsigned)(BATCH * 1310720 / 8 / 256)), 256, 0, stream>>>(
        ctxM16, E1, E2, ctxb);
    // out = ctx @ Wo + bo (BN=128: 256 blocks, full machine, swz)
    gemm4p<float, 128, false, false, true><<<dim3(256, 1, 1), 512, 0, stream>>>(
        ctxb, Wot, out, nullptr, nullptr, nullptr, bo,
        BDIM, BDIM, BDIM, BDIM, 8, 0, 0, 0);
}

// Round 11
// 236.962 us; speedup vs baseline: 1.0273x; 1.0273x over previous
//
#include <hip/hip_runtime.h>
#include <hip/hip_bf16.h>

// Attention: out = softmax_causal((xWq+bq)(xWk+bk)^T / sqrt(D)) (xWv+bv) Wo + bo
// B=4, S=2048, D=1024.  All GEMMs bf16 MFMA 16x16x32, fp32 accumulate.
// R11: BM=128 x BN=128 tiles (LDS 64 KB, VGPR<=128 via __launch_bounds__(512,4))
//      -> 2 blocks/CU so a second resident block fills barrier stalls (m114).
//      Same verified 4-phase counted-vmcnt schedule, re-derived for 4 loads
//      per K-tile: vmcnt(1) at PH0/PH3 ends, >=2 phases cover per load.
//      Pre-pass (cvt + 4 weight transposes + bias concat) fused into ONE
//      kernel.  PV: 2 K-chunks @1024, bf16 partials (validated R10), direct
//      write for rows<1024, 2-way merge above.

typedef __bf16 bf16x8 __attribute__((ext_vector_type(8)));
typedef __bf16 bf16x4 __attribute__((ext_vector_type(4)));
typedef float  f32x4  __attribute__((ext_vector_type(4)));

#define BDIM 1024
#define SDIM 2048
#define BATCH 4

#define BAR()  do { asm volatile("" ::: "memory"); __builtin_amdgcn_s_barrier(); \
                    asm volatile("" ::: "memory"); } while (0)
#define SCB()  __builtin_amdgcn_sched_barrier(0)
#define LGKM0() asm volatile("s_waitcnt lgkmcnt(0)" ::: "memory")

__device__ __forceinline__ void gload_lds16(const void* g, void* l) {
    __builtin_amdgcn_global_load_lds(
        (const __attribute__((address_space(1))) void*)g,
        (__attribute__((address_space(3))) void*)l, 16, 0, 0);
}

// ------------- fused pre-pass: x->bf16, W^T->bf16 (packed), bias concat ------
__global__ __launch_bounds__(256) void prepass(const float* __restrict__ x,
                                               const float* __restrict__ Wq,
                                               const float* __restrict__ Wk,
                                               const float* __restrict__ Wv,
                                               const float* __restrict__ Wo,
                                               const float* __restrict__ bq,
                                               const float* __restrict__ bk,
                                               const float* __restrict__ bv,
                                               __bf16* __restrict__ xb,
                                               __bf16* __restrict__ Wcat,
                                               __bf16* __restrict__ Wot,
                                               float* __restrict__ bcat) {
    const int bid = blockIdx.x;
    const int tid = threadIdx.x;
    if (bid < 8192) {                       // x -> bf16 (float4/lane)
        const long i = ((long)bid * 256 + tid) * 4;
        const float4 v = *(const float4*)(x + i);
        bf16x4 o;
        o[0] = (__bf16)v.x; o[1] = (__bf16)v.y; o[2] = (__bf16)v.z; o[3] = (__bf16)v.w;
        *(bf16x4*)(xb + i) = o;
    } else if (bid < 12288) {               // 4 weight transposes, 32x32 tiles
        __shared__ float tile[32][33];
        const int b2 = bid - 8192;
        const int w = b2 >> 10, t = b2 & 1023;
        const int r0 = (t >> 5) * 32, c0 = (t & 31) * 32;
        const float* src = (w == 0) ? Wq : (w == 1) ? Wk : (w == 2) ? Wv : Wo;
        __bf16* dst = (w < 3) ? (Wcat + (long)w * 1048576) : Wot;
        const int tx = tid & 31, ty = tid >> 5;
        #pragma unroll
        for (int j = ty; j < 32; j += 8)
            tile[j][tx] = src[(long)(r0 + j) * 1024 + (c0 + tx)];
        __syncthreads();
        #pragma unroll
        for (int j = ty; j < 32; j += 8)
            dst[(long)(c0 + j) * 1024 + (r0 + tx)] = (__bf16)tile[tx][j];
    } else {                                // bias concat [bq|bk|bv]
        const int i = (bid - 12288) * 256 + tid;
        if (i < 3072)
            bcat[i] = (i < 1024) ? bq[i] : ((i < 2048) ? bk[i - 1024] : bv[i - 2048]);
    }
}

// ---------------- transpose bf16 (for V^T), 32x32 tiles ----------------
__global__ __launch_bounds__(256) void transpose_bf16(const __bf16* __restrict__ in,
                                                      __bf16* __restrict__ out,
                                                      int ldIn, int ldOut,
                                                      long sIn, long sOut) {
    __shared__ float tile[32][33];
    const long b = blockIdx.z;
    in += b * sIn; out += b * sOut;
    const int r0 = blockIdx.y * 32, c0 = blockIdx.x * 32;
    const int tx = threadIdx.x & 31, ty = threadIdx.x >> 5;
    #pragma unroll
    for (int j = ty; j < 32; j += 8)
        tile[j][tx] = (float)in[(long)(r0 + j) * ldIn + (c0 + tx)];
    __syncthreads();
    #pragma unroll
    for (int j = ty; j < 32; j += 8)
        out[(long)(c0 + j) * ldOut + (r0 + tx)] = (__bf16)tile[tx][j];
}

// ---------- 128 x BN BT GEMM, BK=64, 4-phase counted-vmcnt, 2 blocks/CU ------
// 8 waves (2M x 4N).  Per-wave output 64 x BN/4 = acc[4][NF], NF = BN/64.
//   acc[m][n] m=0,1: rows wm*32 + m*16          (A staging half 0, rows 0-63)
//   acc[m][n] m=2,3: rows 64 + wm*32 + (m-2)*16 (A staging half 1, rows 64-127)
// Loads per K-tile: A-h0 (1), B (NB=BN/64), A-h1 (1).
// Stage order: A-h0(PH0), all B(PH1), A-h1(PH2), none(PH3).
// Guards: PH0-end vmcnt(1) -> A-h1(T) landed (outstanding: A-h0(T+1) only);
//         PH3-end vmcnt(1) -> A-h0(T+1)+B(T+1) landed, A-h1(T+1) flies.
// Every load waits >=2 phases after issue.  vmcnt never 0 mid-loop.
// Staging buffer != read buffer -> no mid-loop lgkm drain needed.
// PVMODE: bz = batch*2 + chunk; K = [chunk*1024, min((by+1)*128, +1024));
//   chunk0/by<8 -> direct bf16 Cd (single contributor);
//   chunk0/by>=8 -> M16 plane (rows-1024); chunk1 -> E1 plane (rows-1024).
template <typename Tout, int BN, bool CSKIP, bool PVMODE, bool SWZ>
__global__ __launch_bounds__(512, 4) void gemm4p(const __bf16* __restrict__ Ag,
                                                 const __bf16* __restrict__ Bg,
                                                 Tout* __restrict__ C0,
                                                 __bf16* __restrict__ M16,
                                                 __bf16* __restrict__ E1,
                                                 __bf16* __restrict__ Cd,
                                                 const float* __restrict__ bias,
                                                 int K, int lda, int ldb, int ldc,
                                                 int nbx, long sA, long sB, long sC) {
    constexpr int NF = BN / 64;
    constexpr int NB = BN / 64;
    int bx, by;
    const int bz = blockIdx.z;
    if (SWZ) {  // XCD-aware contiguous chunks (grid.x % 8 == 0)
        const int flat = blockIdx.x;
        const int w = (flat & 7) * ((int)gridDim.x >> 3) + (flat >> 3);
        bx = w % nbx; by = w / nbx;
    } else { bx = blockIdx.x; by = blockIdx.y; }
    if (CSKIP && bx > by) return;  // BM==BN==128: live iff bx <= by

    const int m0 = by * 128, n0 = bx * BN;
    int kStart = 0, kEnd = K;
    const __bf16* A; const __bf16* B;
    Tout* C = nullptr;
    __bf16* Wout = nullptr;
    int rShift = 0;
    if (PVMODE) {
        const int b = bz >> 1, ch = bz & 1;
        kStart = ch << 10;
        kEnd = min((by + 1) * 128, kStart + 1024);
        if (kEnd <= kStart) return;          // chunk1 live only for by >= 8
        A = Ag + (long)b * sA;
        B = Bg + (long)b * sB;
        if (ch == 0) {
            if (by < 8) { rShift = 0;    Wout = Cd  + (long)b * sC; }
            else        { rShift = 1024; Wout = M16 + (long)b * 1048576; }
        } else          { rShift = 1024; Wout = E1  + (long)b * 1048576; }
    } else {
        A = Ag + (long)bz * sA;
        B = Bg + (long)bz * sB;
        C = C0 + (long)bz * sC;
    }
    const int NT = (kEnd - kStart) >> 6;   // BK=64 tiles (>= 2 always)

    __shared__ __align__(16) __bf16 As[2][8192];     // [128 rows][64 k], swz
    __shared__ __align__(16) __bf16 Bs[2][BN * 64];  // [BN rows][64 k], swz

    const int tid = threadIdx.x;
    const int wid = tid >> 6, l = tid & 63;
    const int wm = wid >> 2, wn = wid & 3;          // wave grid 2(M) x 4(N)
    const int lr = l & 15, lu = l >> 4;

    // ---- staging source offsets (inverse-swizzled global cols, rule #21) ----
    int srcA[2], srcB[NB];
    #pragma unroll
    for (int i = 0; i < 2; ++i) {
        const int beta = i * 8192 + tid * 16;          // linear LDS byte
        const int r = beta >> 7;                       // row (128B rows)
        const int cb = (beta & 127) ^ ((r & 7) << 4);  // unswizzled col byte
        srcA[i] = (m0 + r) * lda + (cb >> 1);
    }
    #pragma unroll
    for (int i = 0; i < NB; ++i) {
        const int beta = i * 8192 + tid * 16;
        const int r = beta >> 7;
        const int cb = (beta & 127) ^ ((r & 7) << 4);
        srcB[i] = (n0 + r) * ldb + (cb >> 1);
    }
    auto stA = [&](int buf, int half, int koff) {   // 1 gload = one 64-row half
        gload_lds16(A + srcA[half] + koff,
                    (char*)&As[buf][0] + half * 8192 + wid * 1024);
    };
    auto stB = [&](int buf, int j, int koff) {      // 1 gload = one B chunk
        gload_lds16(B + srcB[j] + koff,
                    (char*)&Bs[buf][0] + j * 8192 + wid * 1024);
    };

    // ---- swizzled fragment read offsets (elements), lane constants ----
    const int xo  = (lr & 7) << 4;                       // row-derived XOR
    const int c0e = ((lu << 4) ^ xo) >> 1;               // kk=0 col elems
    const int c1e = ((64 + (lu << 4)) ^ xo) >> 1;        // kk=1 col elems
    const int aLo = (wm * 32 + lr) * 64;                 // A half-0 strip base
    const int aHi = (64 + wm * 32 + lr) * 64;            // A half-1 strip base
    const int bBase = (wn * (BN / 4) + lr) * 64;

    f32x4 acc[4][NF] = {};
    bf16x8 aR[2], bR[NF];

    // ---- prologue: stage tile 0 (A-h0, B..., A-h1); A-h1 may stay in flight --
    stA(0, 0, kStart);
    #pragma unroll
    for (int j = 0; j < NB; ++j) stB(0, j, kStart);
    stA(0, 1, kStart);
    asm volatile("s_waitcnt vmcnt(1)" ::: "memory");
    BAR();

    for (int T = 0; T < NT; ++T) {
        const int c = T & 1;
        const bool more = (T + 1 < NT);
        const int k1 = kStart + (T + 1) * 64;
        const __bf16* Ab = &As[c][0];
        const __bf16* Bb = &Bs[c][0];

        // ---- PH0: read A-h0 kk0 (2) + B kk0 (NF) | stage A-h0(T+1) ----
        #pragma unroll
        for (int m = 0; m < 2; ++m) aR[m] = *(const bf16x8*)(Ab + aLo + m * 1024 + c0e);
        #pragma unroll
        for (int n = 0; n < NF; ++n) bR[n] = *(const bf16x8*)(Bb + bBase + n * 1024 + c0e);
        if (more) stA(c ^ 1, 0, k1);
        BAR();
        LGKM0(); SCB();
        __builtin_amdgcn_s_setprio(1);
        #pragma unroll
        for (int m = 0; m < 2; ++m)
            #pragma unroll
            for (int n = 0; n < NF; ++n)
                acc[m][n] = __builtin_amdgcn_mfma_f32_16x16x32_bf16(aR[m], bR[n],
                                                                    acc[m][n], 0, 0, 0);
        __builtin_amdgcn_s_setprio(0);
        if (more) asm volatile("s_waitcnt vmcnt(1)" ::: "memory");  // A-h1(T) in
        else      asm volatile("s_waitcnt vmcnt(0)" ::: "memory");
        BAR();

        // ---- PH1: read A-h1 kk0 (2) | stage all B(T+1) ----
        #pragma unroll
        for (int m = 0; m < 2; ++m) aR[m] = *(const bf16x8*)(Ab + aHi + m * 1024 + c0e);
        if (more) {
            #pragma unroll
            for (int j = 0; j < NB; ++j) stB(c ^ 1, j, k1);
        }
        BAR();
        LGKM0(); SCB();
        __builtin_amdgcn_s_setprio(1);
        #pragma unroll
        for (int m = 0; m < 2; ++m)
            #pragma unroll
            for (int n = 0; n < NF; ++n)
                acc[2 + m][n] = __builtin_amdgcn_mfma_f32_16x16x32_bf16(aR[m], bR[n],
                                                                        acc[2 + m][n], 0, 0, 0);
        __builtin_amdgcn_s_setprio(0);
        BAR();

        // ---- PH2: read A-h0 kk1 (2) + B kk1 (NF) | stage A-h1(T+1) ----
        #pragma unroll
        for (int m = 0; m < 2; ++m) aR[m] = *(const bf16x8*)(Ab + aLo + m * 1024 + c1e);
        #pragma unroll
        for (int n = 0; n < NF; ++n) bR[n] = *(const bf16x8*)(Bb + bBase + n * 1024 + c1e);
        if (more) stA(c ^ 1, 1, k1);
        BAR();
        LGKM0(); SCB();
        __builtin_amdgcn_s_setprio(1);
        #pragma unroll
        for (int m = 0; m < 2; ++m)
            #pragma unroll
            for (int n = 0; n < NF; ++n)
                acc[m][n] = __builtin_amdgcn_mfma_f32_16x16x32_bf16(aR[m], bR[n],
                                                                    acc[m][n], 0, 0, 0);
        __builtin_amdgcn_s_setprio(0);
        BAR();

        // ---- PH3: read A-h1 kk1 (2) | no staging ----
        #pragma unroll
        for (int m = 0; m < 2; ++m) aR[m] = *(const bf16x8*)(Ab + aHi + m * 1024 + c1e);
        BAR();
        LGKM0(); SCB();
        __builtin_amdgcn_s_setprio(1);
        #pragma unroll
        for (int m = 0; m < 2; ++m)
            #pragma unroll
            for (int n = 0; n < NF; ++n)
                acc[2 + m][n] = __builtin_amdgcn_mfma_f32_16x16x32_bf16(aR[m], bR[n],
                                                                        acc[2 + m][n], 0, 0, 0);
        __builtin_amdgcn_s_setprio(0);
        if (more) {  // A-h0(T+1) + B(T+1) landed; A-h1(T+1) flies
            asm volatile("s_waitcnt vmcnt(1)" ::: "memory");
            BAR();
        }
    }

    // epilogue: C/D layout col = lane&15, row = (lane>>4)*4 + reg [m89-verified]
    // acc index mi -> C row m0 + (mi>>1)*64 + wm*32 + (mi&1)*16 + rb
    const int rb = lu * 4, cl = lr;
    #pragma unroll
    for (int n = 0; n < NF; ++n) {
        const int col = n0 + wn * (BN / 4) + n * 16 + cl;
        const float bvv = bias ? bias[col] : 0.f;
        #pragma unroll
        for (int mi = 0; mi < 4; ++mi) {
            const int row = m0 + (mi >> 1) * 64 + wm * 32 + (mi & 1) * 16 + rb;
            #pragma unroll
            for (int r = 0; r < 4; ++r) {
                const float v = acc[mi][n][r] + bvv;
                if constexpr (PVMODE)
                    Wout[(long)(row + r - rShift) * ldc + col] = (__bf16)v;
                else
                    C[(long)(row + r) * ldc + col] = (Tout)v;
            }
        }
    }
}

// ------ merge PV partials (rows 1024..2047): ctxb = bf16(M16 + E1) -----------
__global__ __launch_bounds__(256) void merge2(const __bf16* __restrict__ M16,
                                              const __bf16* __restrict__ E1,
                                              __bf16* __restrict__ out) {
    const long i = ((long)blockIdx.x * 256 + threadIdx.x) * 8;  // [0, B*1048576)
    const long b = i >> 20;
    const long j = i & 1048575;
    const bf16x8 a = *(const bf16x8*)(M16 + b * 1048576 + j);
    const bf16x8 c = *(const bf16x8*)(E1 + b * 1048576 + j);
    bf16x8 o;
    #pragma unroll
    for (int t = 0; t < 8; ++t) o[t] = (__bf16)((float)a[t] + (float)c[t]);
    *(bf16x8*)(out + b * 2097152 + 1048576 + j) = o;
}

// ---------------- causal softmax row kernel (16B/lane, bounded I/O) ----------
__global__ __launch_bounds__(256) void softmax_causal(const __bf16* __restrict__ scores,
                                                      __bf16* __restrict__ P, float scale) {
    const int q = blockIdx.x;
    const long b = blockIdx.y;
    const __bf16* srow = scores + (b * SDIM + q) * (long)SDIM;
    __bf16* prow = P + (b * SDIM + q) * (long)SDIM;
    const int n = q + 1;
    const int kBound = ((q >> 7) + 1) << 7;    // PV reads P cols < kBound only
    const int tid = threadIdx.x;
    const int k0 = tid * 8;
    __shared__ float red[8];

    float vals[8];
    float mx = -1e30f;
    if (k0 < n) {
        const bf16x8 v = *(const bf16x8*)(srow + k0);
        #pragma unroll
        for (int i = 0; i < 8; ++i) {
            const float s = (k0 + i < n) ? (float)v[i] * scale : -1e30f;
            vals[i] = s;
            mx = fmaxf(mx, s);
        }
    } else {
        #pragma unroll
        for (int i = 0; i < 8; ++i) vals[i] = -1e30f;
    }
    #pragma unroll
    for (int o = 32; o > 0; o >>= 1) mx = fmaxf(mx, __shfl_xor(mx, o));
    if ((tid & 63) == 0) red[tid >> 6] = mx;
    __syncthreads();
    mx = fmaxf(fmaxf(red[0], red[1]), fmaxf(red[2], red[3]));

    float p[8];
    float sum = 0.f;
    #pragma unroll
    for (int i = 0; i < 8; ++i) {
        p[i] = __expf(vals[i] - mx);
        sum += p[i];
    }
    #pragma unroll
    for (int o = 32; o > 0; o >>= 1) sum += __shfl_xor(sum, o);
    if ((tid & 63) == 0) red[4 + (tid >> 6)] = sum;
    __syncthreads();
    sum = red[4] + red[5] + red[6] + red[7];

    if (k0 < kBound) {                     // cols >= kBound never read by PV
        const float inv = 1.f / sum;
        bf16x8 o;
        #pragma unroll
        for (int i = 0; i < 8; ++i)
            o[i] = (__bf16)((k0 + i < n) ? p[i] * inv : 0.f);
        *(bf16x8*)(prow + k0) = o;
    }
}

extern "C" void kernel_launch(void* const* d_in, const int* in_sizes, int n_in,
                              void* d_out, int out_size, void* d_ws, size_t ws_size,
                              hipStream_t stream) {
    const float* x  = (const float*)d_in[0];
    // d_in[1] = mask (tril ones) -- causality enforced by index, unused.
    const float* Wq = (const float*)d_in[2];
    const float* bq = (const float*)d_in[3];
    const float* Wk = (const float*)d_in[4];
    const float* bk = (const float*)d_in[5];
    const float* Wv = (const float*)d_in[6];
    const float* bv = (const float*)d_in[7];
    const float* Wo = (const float*)d_in[8];
    const float* bo = (const float*)d_in[9];
    float* out = (float*)d_out;

    char* ws = (char*)d_ws;
    const long XE = (long)BATCH * SDIM * BDIM;    // 8,388,608
    __bf16* xb    = (__bf16*)(ws);                // 16 MiB, dead after QKV
    __bf16* Wcat  = (__bf16*)(ws + 16777216);     // 6 MiB
    __bf16* Wot   = (__bf16*)(ws + 23068672);     // 2 MiB
    float*  bcat  = (float*)(ws + 25165824);      // 12 KiB
    __bf16* QKVb  = (__bf16*)(ws + 25178112);     // 48 MiB (8192 x 3072)
    __bf16* Vtb   = (__bf16*)(ws + 75509760);     // 16 MiB (B x [1024][2048])
    __bf16* Sc    = (__bf16*)(ws + 92286976);     // 32 MiB, dead after softmax
    __bf16* Pb    = (__bf16*)(ws + 25178112);     // alias QKVb[0..32M)
    __bf16* M16   = (__bf16*)(ws + 92286976);     // 8 MiB, alias Sc
    __bf16* E1    = (__bf16*)(ws + 100675584);    // 8 MiB, alias Sc+8M
    __bf16* ctxb  = (__bf16*)(ws + 58732544);     // 16 MiB, alias QKVb[32M..48M)

    const long SD  = (long)SDIM * BDIM;           // 2,097,152
    const long SS  = (long)SDIM * SDIM;           // 4,194,304
    const long SQ3 = (long)SDIM * 3 * BDIM;       // 6,291,456

    // fused pre-pass: cvt x (8192 blocks) + 4 W^T (4096) + bias concat (12)
    prepass<<<dim3(12300), 256, 0, stream>>>(x, Wq, Wk, Wv, Wo, bq, bk, bv,
                                             xb, Wcat, Wot, bcat);

    // QKV[8192][3072] = x @ Wcat^T + bcat  (BM=128/BN=128: 24x64 = 1536 blocks
    // = 3 exact rounds at 2 blocks/CU; XCD swizzle, nbx=24)
    gemm4p<__bf16, 128, false, false, true><<<dim3(1536, 1, 1), 512, 0, stream>>>(
        xb, Wcat, QKVb, nullptr, nullptr, nullptr, bcat,
        BDIM, BDIM, BDIM, 3072, 24, 0, 0, 0);
    // V^T per batch: [S,1024] (stride 3072) -> [1024][S]
    transpose_bf16<<<dim3(32, 64, BATCH), 256, 0, stream>>>(
        QKVb + 2048, Vtb, 3072, SDIM, SQ3, SD);
    // scores = Q @ K^T per batch (causal skip: 544 live of 1024)
    gemm4p<__bf16, 128, true, false, false><<<dim3(16, 16, BATCH), 512, 0, stream>>>(
        QKVb, QKVb + 1024, Sc, nullptr, nullptr, nullptr, nullptr,
        BDIM, 3072, 3072, SDIM, 16, SQ3, SQ3, SS);
    // causal softmax (scale = 1/32)
    softmax_causal<<<dim3(SDIM, BATCH), 256, 0, stream>>>(Sc, Pb, 0.03125f);
    // ctx = P @ V, 2 K-chunks @1024 (768 live blocks); bf16 partials:
    // chunk0/by<8 -> ctxb direct; chunk0/by>=8 -> M16; chunk1 -> E1
    gemm4p<__bf16, 128, false, true, false><<<dim3(8, 16, 2 * BATCH), 512, 0, stream>>>(
        Pb, Vtb, nullptr, M16, E1, ctxb, nullptr,
        SDIM, SDIM, SDIM, BDIM, 8, SS, SD, SD);
    // merge partial planes (rows 1024..2047) -> bf16 ctx
    merge2<<<dim3((unsigned)(BATCH * 1048576 / 8 / 256)), 256, 0, stream>>>(
        M16, E1, ctxb);
    // out = ctx @ Wo + bo (8x64 = 512 blocks = 1 round at 2/CU, swz nbx=8)
    gemm4p<float, 128, false, false, true><<<dim3(512, 1, 1), 512, 0, stream>>>(
        ctxb, Wot, out, nullptr, nullptr, nullptr, bo,
        BDIM, BDIM, BDIM, BDIM, 8, 0, 0, 0);
}

// Round 12
// 229.878 us; speedup vs baseline: 1.0590x; 1.0308x over previous
//
#include <hip/hip_runtime.h>
#include <hip/hip_bf16.h>

// Attention: out = softmax_causal((xWq+bq)(xWk+bk)^T / sqrt(D)) (xWv+bv) Wo + bo
// B=4, S=2048, D=1024.  All GEMMs bf16 MFMA 16x16x32, fp32 accumulate.
// R12: T3-minimum 2-phase GEMM core (catalog recipe, m230-V0): per K-tile
//      { stage(T+1 -> buf^1) FIRST; compute(buf) with compiler-scheduled
//        ds_read||MFMA (no manual lgkm fences, no sched_barrier, no setprio);
//        vmcnt(0); ONE s_barrier }.  1 barrier + 1 vmcnt per K-tile vs R9's 8.
//      Geometry kept from R9/R11 winners: 256xBN tiles (QKV BN=192 = 512
//      blocks = 2 exact rounds; QK^T/PV BN=256; out-proj BN=128 = 256 blocks),
//      T2 swizzle, XCD swizzle, fused prepass, PV 2-chunk bf16 partials.

typedef __bf16 bf16x8 __attribute__((ext_vector_type(8)));
typedef __bf16 bf16x4 __attribute__((ext_vector_type(4)));
typedef float  f32x4  __attribute__((ext_vector_type(4)));

#define BDIM 1024
#define SDIM 2048
#define BATCH 4

#define BAR()  do { asm volatile("" ::: "memory"); __builtin_amdgcn_s_barrier(); \
                    asm volatile("" ::: "memory"); } while (0)

__device__ __forceinline__ void gload_lds16(const void* g, void* l) {
    __builtin_amdgcn_global_load_lds(
        (const __attribute__((address_space(1))) void*)g,
        (__attribute__((address_space(3))) void*)l, 16, 0, 0);
}

// ------------- fused pre-pass: x->bf16, W^T->bf16 (packed), bias concat ------
__global__ __launch_bounds__(256) void prepass(const float* __restrict__ x,
                                               const float* __restrict__ Wq,
                                               const float* __restrict__ Wk,
                                               const float* __restrict__ Wv,
                                               const float* __restrict__ Wo,
                                               const float* __restrict__ bq,
                                               const float* __restrict__ bk,
                                               const float* __restrict__ bv,
                                               __bf16* __restrict__ xb,
                                               __bf16* __restrict__ Wcat,
                                               __bf16* __restrict__ Wot,
                                               float* __restrict__ bcat) {
    const int bid = blockIdx.x;
    const int tid = threadIdx.x;
    if (bid < 8192) {                       // x -> bf16 (float4/lane)
        const long i = ((long)bid * 256 + tid) * 4;
        const float4 v = *(const float4*)(x + i);
        bf16x4 o;
        o[0] = (__bf16)v.x; o[1] = (__bf16)v.y; o[2] = (__bf16)v.z; o[3] = (__bf16)v.w;
        *(bf16x4*)(xb + i) = o;
    } else if (bid < 12288) {               // 4 weight transposes, 32x32 tiles
        __shared__ float tile[32][33];
        const int b2 = bid - 8192;
        const int w = b2 >> 10, t = b2 & 1023;
        const int r0 = (t >> 5) * 32, c0 = (t & 31) * 32;
        const float* src = (w == 0) ? Wq : (w == 1) ? Wk : (w == 2) ? Wv : Wo;
        __bf16* dst = (w < 3) ? (Wcat + (long)w * 1048576) : Wot;
        const int tx = tid & 31, ty = tid >> 5;
        #pragma unroll
        for (int j = ty; j < 32; j += 8)
            tile[j][tx] = src[(long)(r0 + j) * 1024 + (c0 + tx)];
        __syncthreads();
        #pragma unroll
        for (int j = ty; j < 32; j += 8)
            dst[(long)(c0 + j) * 1024 + (r0 + tx)] = (__bf16)tile[tx][j];
    } else {                                // bias concat [bq|bk|bv]
        const int i = (bid - 12288) * 256 + tid;
        if (i < 3072)
            bcat[i] = (i < 1024) ? bq[i] : ((i < 2048) ? bk[i - 1024] : bv[i - 2048]);
    }
}

// ---------------- transpose bf16 (for V^T), 32x32 tiles ----------------
__global__ __launch_bounds__(256) void transpose_bf16(const __bf16* __restrict__ in,
                                                      __bf16* __restrict__ out,
                                                      int ldIn, int ldOut,
                                                      long sIn, long sOut) {
    __shared__ float tile[32][33];
    const long b = blockIdx.z;
    in += b * sIn; out += b * sOut;
    const int r0 = blockIdx.y * 32, c0 = blockIdx.x * 32;
    const int tx = threadIdx.x & 31, ty = threadIdx.x >> 5;
    #pragma unroll
    for (int j = ty; j < 32; j += 8)
        tile[j][tx] = (float)in[(long)(r0 + j) * ldIn + (c0 + tx)];
    __syncthreads();
    #pragma unroll
    for (int j = ty; j < 32; j += 8)
        out[(long)(c0 + j) * ldOut + (r0 + tx)] = (__bf16)tile[tx][j];
}

// ---------- 256 x BN BT GEMM, BK=64, 2-phase single-barrier core -------------
// 8 waves (2M x 4N).  Per-wave output 128 x BN/4 = acc[8][NF], NF = BN/64.
//   acc[m][n]   (m=0..3): rows wm*64 + m*16
//   acc[4+m][n] (m=0..3): rows 128 + wm*64 + m*16
// Per K-tile: { stage tile T+1 into buf^1 (4 + NB gload_lds, issued FIRST so
// the end-of-tile vmcnt(0) drain is covered by ~2000cyc of compute);
// compute(buf): 16+2*NF compiler-scheduled ds_read_b128 + 16*NF MFMA (no
// manual fences -- compiler emits fine-grained lgkmcnt); vmcnt(0); BAR }.
// Race-free: each wave's ds_reads of buf complete before its consuming MFMAs
// (compiler lgkmcnt), which precede the barrier => block-wide reads done
// before next tile's staging overwrites buf; vmcnt(0)+BAR publishes buf^1.
// Swizzle (T2): 128B LDS rows, byte ^= ((row&7)<<4); inverse on global src.
// PVMODE: bz = batch*2 + ch; K = [ch*1024, min((by+1)*256, ch*1024+1024));
//   ch0/by<4 -> direct bf16 Cd (single contributor); ch0/by>=4 -> M16 plane
//   (rows-1024); ch1 (by>=4) -> E1 plane (rows-1024).  merge2 sums planes.
template <typename Tout, int BN, bool CSKIP, bool PVMODE, bool SWZ>
__global__ __launch_bounds__(512, 1) void gemm2p(const __bf16* __restrict__ Ag,
                                                 const __bf16* __restrict__ Bg,
                                                 Tout* __restrict__ C0,
                                                 __bf16* __restrict__ M16,
                                                 __bf16* __restrict__ E1,
                                                 __bf16* __restrict__ Cd,
                                                 const float* __restrict__ bias,
                                                 int K, int lda, int ldb, int ldc,
                                                 int nbx, long sA, long sB, long sC) {
    constexpr int NF = BN / 64;
    constexpr int NB = BN / 64;
    int bx, by;
    const int bz = blockIdx.z;
    if (SWZ) {  // XCD-aware contiguous chunks (grid.x % 8 == 0)
        const int flat = blockIdx.x;
        const int w = (flat & 7) * ((int)gridDim.x >> 3) + (flat >> 3);
        bx = w % nbx; by = w / nbx;
    } else { bx = blockIdx.x; by = blockIdx.y; }
    if (CSKIP && bx * BN > by * 256 + 255) return;  // fully above causal diag

    const int m0 = by * 256, n0 = bx * BN;
    int kStart = 0, kEnd = K;
    const __bf16* A; const __bf16* B;
    Tout* C = nullptr;
    __bf16* Wout = nullptr;
    int rShift = 0;
    if (PVMODE) {
        const int b = bz >> 1, ch = bz & 1;
        kStart = ch << 10;
        kEnd = min((by + 1) * 256, kStart + 1024);
        if (kEnd <= kStart) return;          // chunk1 live only for by >= 4
        A = Ag + (long)b * sA;
        B = Bg + (long)b * sB;
        if (ch == 0) {
            if (by < 4) { rShift = 0;    Wout = Cd  + (long)b * sC; }
            else        { rShift = 1024; Wout = M16 + (long)b * 1048576; }
        } else          { rShift = 1024; Wout = E1  + (long)b * 1048576; }
    } else {
        A = Ag + (long)bz * sA;
        B = Bg + (long)bz * sB;
        C = C0 + (long)bz * sC;
    }
    const int NT = (kEnd - kStart) >> 6;   // BK=64 tiles (>= 4 always)

    __shared__ __align__(16) __bf16 As[2][16384];    // [256 rows][64 k], swz
    __shared__ __align__(16) __bf16 Bs[2][BN * 64];  // [BN rows][64 k], swz

    const int tid = threadIdx.x;
    const int wid = tid >> 6, l = tid & 63;
    const int wm = wid >> 2, wn = wid & 3;          // wave grid 2(M) x 4(N)
    const int lr = l & 15, lu = l >> 4;

    // ---- staging source offsets (inverse-swizzled global cols, rule #21) ----
    int srcA[4], srcB[NB];
    #pragma unroll
    for (int i = 0; i < 4; ++i) {
        const int beta = i * 8192 + tid * 16;          // linear LDS byte
        const int r = beta >> 7;                       // row (128B rows)
        const int cb = (beta & 127) ^ ((r & 7) << 4);  // unswizzled col byte
        srcA[i] = (m0 + r) * lda + (cb >> 1);
    }
    #pragma unroll
    for (int i = 0; i < NB; ++i) {
        const int beta = i * 8192 + tid * 16;
        const int r = beta >> 7;
        const int cb = (beta & 127) ^ ((r & 7) << 4);
        srcB[i] = (n0 + r) * ldb + (cb >> 1);
    }
    auto stage = [&](int buf, int koff) {
        #pragma unroll
        for (int i = 0; i < 4; ++i)
            gload_lds16(A + srcA[i] + koff,
                        (char*)&As[buf][0] + i * 8192 + wid * 1024);
        #pragma unroll
        for (int j = 0; j < NB; ++j)
            gload_lds16(B + srcB[j] + koff,
                        (char*)&Bs[buf][0] + j * 8192 + wid * 1024);
    };

    // ---- swizzled fragment read offsets (elements), lane constants ----
    const int xo  = (lr & 7) << 4;                       // row-derived XOR
    const int c0e = ((lu << 4) ^ xo) >> 1;               // kk=0 col elems
    const int c1e = ((64 + (lu << 4)) ^ xo) >> 1;        // kk=1 col elems
    const int aLo = (wm * 64 + lr) * 64;                 // rows wm*64 + m*16
    const int aHi = (128 + wm * 64 + lr) * 64;           // rows 128 + wm*64 ..
    const int bBase = (wn * (BN / 4) + lr) * 64;

    f32x4 acc[8][NF] = {};

    // ---- prologue: stage tile 0, publish ----
    stage(0, kStart);
    asm volatile("s_waitcnt vmcnt(0)" ::: "memory");
    BAR();

    for (int T = 0; T < NT; ++T) {
        const int c = T & 1;
        const bool more = (T + 1 < NT);
        if (more) stage(c ^ 1, kStart + (T + 1) * 64);   // issue loads FIRST

        // compute on buf c -- compiler schedules ds_read || MFMA freely
        const __bf16* Ab = &As[c][0];
        const __bf16* Bb = &Bs[c][0];
        #pragma unroll
        for (int kk = 0; kk < 2; ++kk) {
            const int ce = kk ? c1e : c0e;
            bf16x8 aR[8], bR[NF];
            #pragma unroll
            for (int m = 0; m < 4; ++m) {
                aR[m]     = *(const bf16x8*)(Ab + aLo + m * 1024 + ce);
                aR[4 + m] = *(const bf16x8*)(Ab + aHi + m * 1024 + ce);
            }
            #pragma unroll
            for (int n = 0; n < NF; ++n)
                bR[n] = *(const bf16x8*)(Bb + bBase + n * 1024 + ce);
            #pragma unroll
            for (int m = 0; m < 8; ++m)
                #pragma unroll
                for (int n = 0; n < NF; ++n)
                    acc[m][n] = __builtin_amdgcn_mfma_f32_16x16x32_bf16(
                        aR[m], bR[n], acc[m][n], 0, 0, 0);
        }

        if (more) {
            asm volatile("s_waitcnt vmcnt(0)" ::: "memory");  // buf c^1 landed
            BAR();                                            // publish
        }
    }

    // epilogue: C/D layout col = lane&15, row = (lane>>4)*4 + reg [m89-verified]
    // acc index mi -> C row m0 + (mi>>2)*128 + wm*64 + (mi&3)*16 + rb
    const int rb = lu * 4, cl = lr;
    #pragma unroll
    for (int n = 0; n < NF; ++n) {
        const int col = n0 + wn * (BN / 4) + n * 16 + cl;
        const float bvv = bias ? bias[col] : 0.f;
        #pragma unroll
        for (int mi = 0; mi < 8; ++mi) {
            const int row = m0 + (mi >> 2) * 128 + wm * 64 + (mi & 3) * 16 + rb;
            #pragma unroll
            for (int r = 0; r < 4; ++r) {
                const float v = acc[mi][n][r] + bvv;
                if constexpr (PVMODE)
                    Wout[(long)(row + r - rShift) * ldc + col] = (__bf16)v;
                else
                    C[(long)(row + r) * ldc + col] = (Tout)v;
            }
        }
    }
}

// ------ merge PV partials (rows 1024..2047): ctxb = bf16(M16 + E1) -----------
__global__ __launch_bounds__(256) void merge2(const __bf16* __restrict__ M16,
                                              const __bf16* __restrict__ E1,
                                              __bf16* __restrict__ out) {
    const long i = ((long)blockIdx.x * 256 + threadIdx.x) * 8;  // [0, B*1048576)
    const long b = i >> 20;
    const long j = i & 1048575;
    const bf16x8 a = *(const bf16x8*)(M16 + b * 1048576 + j);
    const bf16x8 c = *(const bf16x8*)(E1 + b * 1048576 + j);
    bf16x8 o;
    #pragma unroll
    for (int t = 0; t < 8; ++t) o[t] = (__bf16)((float)a[t] + (float)c[t]);
    *(bf16x8*)(out + b * 2097152 + 1048576 + j) = o;
}

// ---------------- causal softmax row kernel (16B/lane, bounded I/O) ----------
__global__ __launch_bounds__(256) void softmax_causal(const __bf16* __restrict__ scores,
                                                      __bf16* __restrict__ P, float scale) {
    const int q = blockIdx.x;
    const long b = blockIdx.y;
    const __bf16* srow = scores + (b * SDIM + q) * (long)SDIM;
    __bf16* prow = P + (b * SDIM + q) * (long)SDIM;
    const int n = q + 1;
    const int kBound = ((q >> 8) + 1) << 8;    // PV reads P cols < kBound only
    const int tid = threadIdx.x;
    const int k0 = tid * 8;
    __shared__ float red[8];

    float vals[8];
    float mx = -1e30f;
    if (k0 < n) {
        const bf16x8 v = *(const bf16x8*)(srow + k0);
        #pragma unroll
        for (int i = 0; i < 8; ++i) {
            const float s = (k0 + i < n) ? (float)v[i] * scale : -1e30f;
            vals[i] = s;
            mx = fmaxf(mx, s);
        }
    } else {
        #pragma unroll
        for (int i = 0; i < 8; ++i) vals[i] = -1e30f;
    }
    #pragma unroll
    for (int o = 32; o > 0; o >>= 1) mx = fmaxf(mx, __shfl_xor(mx, o));
    if ((tid & 63) == 0) red[tid >> 6] = mx;
    __syncthreads();
    mx = fmaxf(fmaxf(red[0], red[1]), fmaxf(red[2], red[3]));

    float p[8];
    float sum = 0.f;
    #pragma unroll
    for (int i = 0; i < 8; ++i) {
        p[i] = __expf(vals[i] - mx);
        sum += p[i];
    }
    #pragma unroll
    for (int o = 32; o > 0; o >>= 1) sum += __shfl_xor(sum, o);
    if ((tid & 63) == 0) red[4 + (tid >> 6)] = sum;
    __syncthreads();
    sum = red[4] + red[5] + red[6] + red[7];

    if (k0 < kBound) {                     // cols >= kBound never read by PV
        const float inv = 1.f / sum;
        bf16x8 o;
        #pragma unroll
        for (int i = 0; i < 8; ++i)
            o[i] = (__bf16)((k0 + i < n) ? p[i] * inv : 0.f);
        *(bf16x8*)(prow + k0) = o;
    }
}

extern "C" void kernel_launch(void* const* d_in, const int* in_sizes, int n_in,
                              void* d_out, int out_size, void* d_ws, size_t ws_size,
                              hipStream_t stream) {
    const float* x  = (const float*)d_in[0];
    // d_in[1] = mask (tril ones) -- causality enforced by index, unused.
    const float* Wq = (const float*)d_in[2];
    const float* bq = (const float*)d_in[3];
    const float* Wk = (const float*)d_in[4];
    const float* bk = (const float*)d_in[5];
    const float* Wv = (const float*)d_in[6];
    const float* bv = (const float*)d_in[7];
    const float* Wo = (const float*)d_in[8];
    const float* bo = (const float*)d_in[9];
    float* out = (float*)d_out;

    char* ws = (char*)d_ws;
    const long XE = (long)BATCH * SDIM * BDIM;    // 8,388,608
    __bf16* xb    = (__bf16*)(ws);                // 16 MiB, dead after QKV
    __bf16* Wcat  = (__bf16*)(ws + 16777216);     // 6 MiB
    __bf16* Wot   = (__bf16*)(ws + 23068672);     // 2 MiB
    float*  bcat  = (float*)(ws + 25165824);      // 12 KiB
    __bf16* QKVb  = (__bf16*)(ws + 25178112);     // 48 MiB (8192 x 3072)
    __bf16* Vtb   = (__bf16*)(ws + 75509760);     // 16 MiB (B x [1024][2048])
    __bf16* Sc    = (__bf16*)(ws + 92286976);     // 32 MiB, dead after softmax
    __bf16* Pb    = (__bf16*)(ws + 25178112);     // alias QKVb[0..32M)
    __bf16* M16   = (__bf16*)(ws + 92286976);     // 8 MiB, alias Sc
    __bf16* E1    = (__bf16*)(ws + 100675584);    // 8 MiB, alias Sc+8M
    __bf16* ctxb  = (__bf16*)(ws + 58732544);     // 16 MiB, alias QKVb[32M..48M)

    const long SD  = (long)SDIM * BDIM;           // 2,097,152
    const long SS  = (long)SDIM * SDIM;           // 4,194,304
    const long SQ3 = (long)SDIM * 3 * BDIM;       // 6,291,456

    // fused pre-pass: cvt x (8192 blocks) + 4 W^T (4096) + bias concat (12)
    prepass<<<dim3(12300), 256, 0, stream>>>(x, Wq, Wk, Wv, Wo, bq, bk, bv,
                                             xb, Wcat, Wot, bcat);

    // QKV[8192][3072] = x @ Wcat^T + bcat (BN=192: 512 blocks = 2 exact rounds)
    gemm2p<__bf16, 192, false, false, true><<<dim3(512, 1, 1), 512, 0, stream>>>(
        xb, Wcat, QKVb, nullptr, nullptr, nullptr, bcat,
        BDIM, BDIM, BDIM, 3072, 16, 0, 0, 0);
    // V^T per batch: [S,1024] (stride 3072) -> [1024][S]
    transpose_bf16<<<dim3(32, 64, BATCH), 256, 0, stream>>>(
        QKVb + 2048, Vtb, 3072, SDIM, SQ3, SD);
    // scores = Q @ K^T per batch (causal tile skip; 144 live blocks)
    gemm2p<__bf16, 256, true, false, false><<<dim3(8, 8, BATCH), 512, 0, stream>>>(
        QKVb, QKVb + 1024, Sc, nullptr, nullptr, nullptr, nullptr,
        BDIM, 3072, 3072, SDIM, 8, SQ3, SQ3, SS);
    // causal softmax (scale = 1/32)
    softmax_causal<<<dim3(SDIM, BATCH), 256, 0, stream>>>(Sc, Pb, 0.03125f);
    // ctx = P @ V, 2 K-chunks @1024 (192 live blocks); bf16 partials:
    // ch0/by<4 -> ctxb direct; ch0/by>=4 -> M16; ch1 -> E1
    gemm2p<__bf16, 256, false, true, false><<<dim3(4, 8, 2 * BATCH), 512, 0, stream>>>(
        Pb, Vtb, nullptr, M16, E1, ctxb, nullptr,
        SDIM, SDIM, SDIM, BDIM, 4, SS, SD, SD);
    // merge partial planes (rows 1024..2047) -> bf16 ctx
    merge2<<<dim3((unsigned)(BATCH * 1048576 / 8 / 256)), 256, 0, stream>>>(
        M16, E1, ctxb);
    // out = ctx @ Wo + bo (BN=128: 256 blocks = full machine, swz)
    gemm2p<float, 128, false, false, true><<<dim3(256, 1, 1), 512, 0, stream>>>(
        ctxb, Wot, out, nullptr, nullptr, nullptr, bo,
        BDIM, BDIM, BDIM, BDIM, 8, 0, 0, 0);
}

// Round 13
// 217.639 us; speedup vs baseline: 1.1185x; 1.0562x over previous
//
#include <hip/hip_runtime.h>
#include <hip/hip_bf16.h>

// Attention: out = softmax_causal((xWq+bq)(xWk+bk)^T / sqrt(D)) (xWv+bv) Wo + bo
// B=4, S=2048, D=1024.  All GEMMs bf16 MFMA 16x16x32, fp32 accumulate.
// R13: R12's T3-minimum 2-phase GEMM core kept verbatim (plateau-verified).
//      NEW: QKV epilogue writes V directly TRANSPOSED into Vtb (cols>=2048
//      never touch QKVb -- nothing reads them); transpose kernel removed.
//      Saves ~16 MB writes + 32 MB transpose traffic + 1 launch.

typedef __bf16 bf16x8 __attribute__((ext_vector_type(8)));
typedef __bf16 bf16x4 __attribute__((ext_vector_type(4)));
typedef float  f32x4  __attribute__((ext_vector_type(4)));

#define BDIM 1024
#define SDIM 2048
#define BATCH 4

#define BAR()  do { asm volatile("" ::: "memory"); __builtin_amdgcn_s_barrier(); \
                    asm volatile("" ::: "memory"); } while (0)

__device__ __forceinline__ void gload_lds16(const void* g, void* l) {
    __builtin_amdgcn_global_load_lds(
        (const __attribute__((address_space(1))) void*)g,
        (__attribute__((address_space(3))) void*)l, 16, 0, 0);
}

// ------------- fused pre-pass: x->bf16, W^T->bf16 (packed), bias concat ------
__global__ __launch_bounds__(256) void prepass(const float* __restrict__ x,
                                               const float* __restrict__ Wq,
                                               const float* __restrict__ Wk,
                                               const float* __restrict__ Wv,
                                               const float* __restrict__ Wo,
                                               const float* __restrict__ bq,
                                               const float* __restrict__ bk,
                                               const float* __restrict__ bv,
                                               __bf16* __restrict__ xb,
                                               __bf16* __restrict__ Wcat,
                                               __bf16* __restrict__ Wot,
                                               float* __restrict__ bcat) {
    const int bid = blockIdx.x;
    const int tid = threadIdx.x;
    if (bid < 8192) {                       // x -> bf16 (float4/lane)
        const long i = ((long)bid * 256 + tid) * 4;
        const float4 v = *(const float4*)(x + i);
        bf16x4 o;
        o[0] = (__bf16)v.x; o[1] = (__bf16)v.y; o[2] = (__bf16)v.z; o[3] = (__bf16)v.w;
        *(bf16x4*)(xb + i) = o;
    } else if (bid < 12288) {               // 4 weight transposes, 32x32 tiles
        __shared__ float tile[32][33];
        const int b2 = bid - 8192;
        const int w = b2 >> 10, t = b2 & 1023;
        const int r0 = (t >> 5) * 32, c0 = (t & 31) * 32;
        const float* src = (w == 0) ? Wq : (w == 1) ? Wk : (w == 2) ? Wv : Wo;
        __bf16* dst = (w < 3) ? (Wcat + (long)w * 1048576) : Wot;
        const int tx = tid & 31, ty = tid >> 5;
        #pragma unroll
        for (int j = ty; j < 32; j += 8)
            tile[j][tx] = src[(long)(r0 + j) * 1024 + (c0 + tx)];
        __syncthreads();
        #pragma unroll
        for (int j = ty; j < 32; j += 8)
            dst[(long)(c0 + j) * 1024 + (r0 + tx)] = (__bf16)tile[tx][j];
    } else {                                // bias concat [bq|bk|bv]
        const int i = (bid - 12288) * 256 + tid;
        if (i < 3072)
            bcat[i] = (i < 1024) ? bq[i] : ((i < 2048) ? bk[i - 1024] : bv[i - 2048]);
    }
}

// ---------- 256 x BN BT GEMM, BK=64, 2-phase single-barrier core -------------
// 8 waves (2M x 4N).  Per-wave output 128 x BN/4 = acc[8][NF], NF = BN/64.
// Per K-tile: { stage tile T+1 into buf^1 FIRST (covers the end-of-tile
// vmcnt(0) drain with ~2000cyc of compute); compute(buf) compiler-scheduled;
// vmcnt(0); ONE s_barrier }.  Race-free per R12 proof.
// Swizzle (T2): 128B LDS rows, byte ^= ((row&7)<<4); inverse on global src.
// VTOUT (QKV): cols >= 2048 are V -- written TRANSPOSED to Vt[b][col-2048][s]
//   (8B bf16x4 per thread, s = row&2047 aligned 4); QKVb never receives them.
// PVMODE: bz = batch*2 + ch; K = [ch*1024, min((by+1)*256, ch*1024+1024));
//   ch0/by<4 -> direct bf16 Cd; ch0/by>=4 -> M16 plane (rows-1024);
//   ch1 (by>=4) -> E1 plane (rows-1024).  merge2 sums planes.
template <typename Tout, int BN, bool CSKIP, bool PVMODE, bool SWZ, bool VTOUT>
__global__ __launch_bounds__(512, 1) void gemm2p(const __bf16* __restrict__ Ag,
                                                 const __bf16* __restrict__ Bg,
                                                 Tout* __restrict__ C0,
                                                 __bf16* __restrict__ M16,
                                                 __bf16* __restrict__ E1,
                                                 __bf16* __restrict__ Cd,
                                                 __bf16* __restrict__ Vt,
                                                 const float* __restrict__ bias,
                                                 int K, int lda, int ldb, int ldc,
                                                 int nbx, long sA, long sB, long sC) {
    constexpr int NF = BN / 64;
    constexpr int NB = BN / 64;
    int bx, by;
    const int bz = blockIdx.z;
    if (SWZ) {  // XCD-aware contiguous chunks (grid.x % 8 == 0)
        const int flat = blockIdx.x;
        const int w = (flat & 7) * ((int)gridDim.x >> 3) + (flat >> 3);
        bx = w % nbx; by = w / nbx;
    } else { bx = blockIdx.x; by = blockIdx.y; }
    if (CSKIP && bx * BN > by * 256 + 255) return;  // fully above causal diag

    const int m0 = by * 256, n0 = bx * BN;
    int kStart = 0, kEnd = K;
    const __bf16* A; const __bf16* B;
    Tout* C = nullptr;
    __bf16* Wout = nullptr;
    int rShift = 0;
    if (PVMODE) {
        const int b = bz >> 1, ch = bz & 1;
        kStart = ch << 10;
        kEnd = min((by + 1) * 256, kStart + 1024);
        if (kEnd <= kStart) return;          // chunk1 live only for by >= 4
        A = Ag + (long)b * sA;
        B = Bg + (long)b * sB;
        if (ch == 0) {
            if (by < 4) { rShift = 0;    Wout = Cd  + (long)b * sC; }
            else        { rShift = 1024; Wout = M16 + (long)b * 1048576; }
        } else          { rShift = 1024; Wout = E1  + (long)b * 1048576; }
    } else {
        A = Ag + (long)bz * sA;
        B = Bg + (long)bz * sB;
        C = C0 + (long)bz * sC;
    }
    const int NT = (kEnd - kStart) >> 6;   // BK=64 tiles (>= 4 always)

    __shared__ __align__(16) __bf16 As[2][16384];    // [256 rows][64 k], swz
    __shared__ __align__(16) __bf16 Bs[2][BN * 64];  // [BN rows][64 k], swz

    const int tid = threadIdx.x;
    const int wid = tid >> 6, l = tid & 63;
    const int wm = wid >> 2, wn = wid & 3;          // wave grid 2(M) x 4(N)
    const int lr = l & 15, lu = l >> 4;

    // ---- staging source offsets (inverse-swizzled global cols, rule #21) ----
    int srcA[4], srcB[NB];
    #pragma unroll
    for (int i = 0; i < 4; ++i) {
        const int beta = i * 8192 + tid * 16;          // linear LDS byte
        const int r = beta >> 7;                       // row (128B rows)
        const int cb = (beta & 127) ^ ((r & 7) << 4);  // unswizzled col byte
        srcA[i] = (m0 + r) * lda + (cb >> 1);
    }
    #pragma unroll
    for (int i = 0; i < NB; ++i) {
        const int beta = i * 8192 + tid * 16;
        const int r = beta >> 7;
        const int cb = (beta & 127) ^ ((r & 7) << 4);
        srcB[i] = (n0 + r) * ldb + (cb >> 1);
    }
    auto stage = [&](int buf, int koff) {
        #pragma unroll
        for (int i = 0; i < 4; ++i)
            gload_lds16(A + srcA[i] + koff,
                        (char*)&As[buf][0] + i * 8192 + wid * 1024);
        #pragma unroll
        for (int j = 0; j < NB; ++j)
            gload_lds16(B + srcB[j] + koff,
                        (char*)&Bs[buf][0] + j * 8192 + wid * 1024);
    };

    // ---- swizzled fragment read offsets (elements), lane constants ----
    const int xo  = (lr & 7) << 4;                       // row-derived XOR
    const int c0e = ((lu << 4) ^ xo) >> 1;               // kk=0 col elems
    const int c1e = ((64 + (lu << 4)) ^ xo) >> 1;        // kk=1 col elems
    const int aLo = (wm * 64 + lr) * 64;                 // rows wm*64 + m*16
    const int aHi = (128 + wm * 64 + lr) * 64;           // rows 128 + wm*64 ..
    const int bBase = (wn * (BN / 4) + lr) * 64;

    f32x4 acc[8][NF] = {};

    // ---- prologue: stage tile 0, publish ----
    stage(0, kStart);
    asm volatile("s_waitcnt vmcnt(0)" ::: "memory");
    BAR();

    for (int T = 0; T < NT; ++T) {
        const int c = T & 1;
        const bool more = (T + 1 < NT);
        if (more) stage(c ^ 1, kStart + (T + 1) * 64);   // issue loads FIRST

        // compute on buf c -- compiler schedules ds_read || MFMA freely
        const __bf16* Ab = &As[c][0];
        const __bf16* Bb = &Bs[c][0];
        #pragma unroll
        for (int kk = 0; kk < 2; ++kk) {
            const int ce = kk ? c1e : c0e;
            bf16x8 aR[8], bR[NF];
            #pragma unroll
            for (int m = 0; m < 4; ++m) {
                aR[m]     = *(const bf16x8*)(Ab + aLo + m * 1024 + ce);
                aR[4 + m] = *(const bf16x8*)(Ab + aHi + m * 1024 + ce);
            }
            #pragma unroll
            for (int n = 0; n < NF; ++n)
                bR[n] = *(const bf16x8*)(Bb + bBase + n * 1024 + ce);
            #pragma unroll
            for (int m = 0; m < 8; ++m)
                #pragma unroll
                for (int n = 0; n < NF; ++n)
                    acc[m][n] = __builtin_amdgcn_mfma_f32_16x16x32_bf16(
                        aR[m], bR[n], acc[m][n], 0, 0, 0);
        }

        if (more) {
            asm volatile("s_waitcnt vmcnt(0)" ::: "memory");  // buf c^1 landed
            BAR();                                            // publish
        }
    }

    // epilogue: C/D layout col = lane&15, row = (lane>>4)*4 + reg [m89-verified]
    // acc index mi -> C row m0 + (mi>>2)*128 + wm*64 + (mi&3)*16 + rb
    const int rb = lu * 4, cl = lr;
    #pragma unroll
    for (int n = 0; n < NF; ++n) {
        const int col = n0 + wn * (BN / 4) + n * 16 + cl;
        const float bvv = bias ? bias[col] : 0.f;
        #pragma unroll
        for (int mi = 0; mi < 8; ++mi) {
            const int row = m0 + (mi >> 2) * 128 + wm * 64 + (mi & 3) * 16 + rb;
            if (VTOUT && col >= 2048) {
                // V output: write transposed Vt[b][col-2048][s..s+3] (8B store)
                const int b = row >> 11, s = row & 2047, dd = col - 2048;
                bf16x4 o;
                #pragma unroll
                for (int r = 0; r < 4; ++r) o[r] = (__bf16)(acc[mi][n][r] + bvv);
                *(bf16x4*)(Vt + (long)b * 2097152 + (long)dd * 2048 + s) = o;
            } else {
                #pragma unroll
                for (int r = 0; r < 4; ++r) {
                    const float v = acc[mi][n][r] + bvv;
                    if constexpr (PVMODE)
                        Wout[(long)(row + r - rShift) * ldc + col] = (__bf16)v;
                    else
                        C[(long)(row + r) * ldc + col] = (Tout)v;
                }
            }
        }
    }
}

// ------ merge PV partials (rows 1024..2047): ctxb = bf16(M16 + E1) -----------
__global__ __launch_bounds__(256) void merge2(const __bf16* __restrict__ M16,
                                              const __bf16* __restrict__ E1,
                                              __bf16* __restrict__ out) {
    const long i = ((long)blockIdx.x * 256 + threadIdx.x) * 8;  // [0, B*1048576)
    const long b = i >> 20;
    const long j = i & 1048575;
    const bf16x8 a = *(const bf16x8*)(M16 + b * 1048576 + j);
    const bf16x8 c = *(const bf16x8*)(E1 + b * 1048576 + j);
    bf16x8 o;
    #pragma unroll
    for (int t = 0; t < 8; ++t) o[t] = (__bf16)((float)a[t] + (float)c[t]);
    *(bf16x8*)(out + b * 2097152 + 1048576 + j) = o;
}

// ---------------- causal softmax row kernel (16B/lane, bounded I/O) ----------
__global__ __launch_bounds__(256) void softmax_causal(const __bf16* __restrict__ scores,
                                                      __bf16* __restrict__ P, float scale) {
    const int q = blockIdx.x;
    const long b = blockIdx.y;
    const __bf16* srow = scores + (b * SDIM + q) * (long)SDIM;
    __bf16* prow = P + (b * SDIM + q) * (long)SDIM;
    const int n = q + 1;
    const int kBound = ((q >> 8) + 1) << 8;    // PV reads P cols < kBound only
    const int tid = threadIdx.x;
    const int k0 = tid * 8;
    __shared__ float red[8];

    float vals[8];
    float mx = -1e30f;
    if (k0 < n) {
        const bf16x8 v = *(const bf16x8*)(srow + k0);
        #pragma unroll
        for (int i = 0; i < 8; ++i) {
            const float s = (k0 + i < n) ? (float)v[i] * scale : -1e30f;
            vals[i] = s;
            mx = fmaxf(mx, s);
        }
    } else {
        #pragma unroll
        for (int i = 0; i < 8; ++i) vals[i] = -1e30f;
    }
    #pragma unroll
    for (int o = 32; o > 0; o >>= 1) mx = fmaxf(mx, __shfl_xor(mx, o));
    if ((tid & 63) == 0) red[tid >> 6] = mx;
    __syncthreads();
    mx = fmaxf(fmaxf(red[0], red[1]), fmaxf(red[2], red[3]));

    float p[8];
    float sum = 0.f;
    #pragma unroll
    for (int i = 0; i < 8; ++i) {
        p[i] = __expf(vals[i] - mx);
        sum += p[i];
    }
    #pragma unroll
    for (int o = 32; o > 0; o >>= 1) sum += __shfl_xor(sum, o);
    if ((tid & 63) == 0) red[4 + (tid >> 6)] = sum;
    __syncthreads();
    sum = red[4] + red[5] + red[6] + red[7];

    if (k0 < kBound) {                     // cols >= kBound never read by PV
        const float inv = 1.f / sum;
        bf16x8 o;
        #pragma unroll
        for (int i = 0; i < 8; ++i)
            o[i] = (__bf16)((k0 + i < n) ? p[i] * inv : 0.f);
        *(bf16x8*)(prow + k0) = o;
    }
}

extern "C" void kernel_launch(void* const* d_in, const int* in_sizes, int n_in,
                              void* d_out, int out_size, void* d_ws, size_t ws_size,
                              hipStream_t stream) {
    const float* x  = (const float*)d_in[0];
    // d_in[1] = mask (tril ones) -- causality enforced by index, unused.
    const float* Wq = (const float*)d_in[2];
    const float* bq = (const float*)d_in[3];
    const float* Wk = (const float*)d_in[4];
    const float* bk = (const float*)d_in[5];
    const float* Wv = (const float*)d_in[6];
    const float* bv = (const float*)d_in[7];
    const float* Wo = (const float*)d_in[8];
    const float* bo = (const float*)d_in[9];
    float* out = (float*)d_out;

    char* ws = (char*)d_ws;
    const long XE = (long)BATCH * SDIM * BDIM;    // 8,388,608
    __bf16* xb    = (__bf16*)(ws);                // 16 MiB, dead after QKV
    __bf16* Wcat  = (__bf16*)(ws + 16777216);     // 6 MiB
    __bf16* Wot   = (__bf16*)(ws + 23068672);     // 2 MiB
    float*  bcat  = (float*)(ws + 25165824);      // 12 KiB
    __bf16* QKVb  = (__bf16*)(ws + 25178112);     // 48 MiB (8192 x 3072; V cols unused)
    __bf16* Vtb   = (__bf16*)(ws + 75509760);     // 16 MiB (B x [1024][2048])
    __bf16* Sc    = (__bf16*)(ws + 92286976);     // 32 MiB, dead after softmax
    __bf16* Pb    = (__bf16*)(ws + 25178112);     // alias QKVb[0..32M)
    __bf16* M16   = (__bf16*)(ws + 92286976);     // 8 MiB, alias Sc
    __bf16* E1    = (__bf16*)(ws + 100675584);    // 8 MiB, alias Sc+8M
    __bf16* ctxb  = (__bf16*)(ws + 58732544);     // 16 MiB, alias QKVb[32M..48M)

    const long SD  = (long)SDIM * BDIM;           // 2,097,152
    const long SS  = (long)SDIM * SDIM;           // 4,194,304
    const long SQ3 = (long)SDIM * 3 * BDIM;       // 6,291,456

    // fused pre-pass: cvt x (8192 blocks) + 4 W^T (4096) + bias concat (12)
    prepass<<<dim3(12300), 256, 0, stream>>>(x, Wq, Wk, Wv, Wo, bq, bk, bv,
                                             xb, Wcat, Wot, bcat);

    // QKV: Q,K cols -> QKVb; V cols -> Vtb transposed (BN=192: 512 blocks)
    gemm2p<__bf16, 192, false, false, true, true><<<dim3(512, 1, 1), 512, 0, stream>>>(
        xb, Wcat, QKVb, nullptr, nullptr, nullptr, Vtb, bcat,
        BDIM, BDIM, BDIM, 3072, 16, 0, 0, 0);
    // scores = Q @ K^T per batch (causal tile skip; 144 live blocks)
    gemm2p<__bf16, 256, true, false, false, false><<<dim3(8, 8, BATCH), 512, 0, stream>>>(
        QKVb, QKVb + 1024, Sc, nullptr, nullptr, nullptr, nullptr, nullptr,
        BDIM, 3072, 3072, SDIM, 8, SQ3, SQ3, SS);
    // causal softmax (scale = 1/32)
    softmax_causal<<<dim3(SDIM, BATCH), 256, 0, stream>>>(Sc, Pb, 0.03125f);
    // ctx = P @ V, 2 K-chunks @1024 (192 live blocks); bf16 partials:
    // ch0/by<4 -> ctxb direct; ch0/by>=4 -> M16; ch1 -> E1
    gemm2p<__bf16, 256, false, true, false, false><<<dim3(4, 8, 2 * BATCH), 512, 0, stream>>>(
        Pb, Vtb, nullptr, M16, E1, ctxb, nullptr, nullptr,
        SDIM, SDIM, SDIM, BDIM, 4, SS, SD, SD);
    // merge partial planes (rows 1024..2047) -> bf16 ctx
    merge2<<<dim3((unsigned)(BATCH * 1048576 / 8 / 256)), 256, 0, stream>>>(
        M16, E1, ctxb);
    // out = ctx @ Wo + bo (BN=128: 256 blocks = full machine, swz)
    gemm2p<float, 128, false, false, true, false><<<dim3(256, 1, 1), 512, 0, stream>>>(
        ctxb, Wot, out, nullptr, nullptr, nullptr, nullptr, bo,
        BDIM, BDIM, BDIM, BDIM, 8, 0, 0, 0);
}

// Round 14
// 182.493 us; speedup vs baseline: 1.3339x; 1.1926x over previous
//
#include <hip/hip_runtime.h>
#include <hip/hip_bf16.h>

// Attention: out = softmax_causal((xWq+bq)(xWk+bk)^T / sqrt(D)) (xWv+bv) Wo + bo
// B=4, S=2048, D=1024.  All GEMMs bf16 MFMA 16x16x32, fp32 accumulate.
// R14: R13 + coalesced Vt epilogue: V columns bounce through LDS (col-stride
//      528B image, ds_write_b64 in / ds_read 16B out) and leave as 16B
//      coalesced global stores instead of 8B scatters.  GEMM core unchanged.

typedef __bf16 bf16x8 __attribute__((ext_vector_type(8)));
typedef __bf16 bf16x4 __attribute__((ext_vector_type(4)));
typedef float  f32x4  __attribute__((ext_vector_type(4)));

#define BDIM 1024
#define SDIM 2048
#define BATCH 4

#define BAR()  do { asm volatile("" ::: "memory"); __builtin_amdgcn_s_barrier(); \
                    asm volatile("" ::: "memory"); } while (0)

__device__ __forceinline__ void gload_lds16(const void* g, void* l) {
    __builtin_amdgcn_global_load_lds(
        (const __attribute__((address_space(1))) void*)g,
        (__attribute__((address_space(3))) void*)l, 16, 0, 0);
}

// ------------- fused pre-pass: x->bf16, W^T->bf16 (packed), bias concat ------
__global__ __launch_bounds__(256) void prepass(const float* __restrict__ x,
                                               const float* __restrict__ Wq,
                                               const float* __restrict__ Wk,
                                               const float* __restrict__ Wv,
                                               const float* __restrict__ Wo,
                                               const float* __restrict__ bq,
                                               const float* __restrict__ bk,
                                               const float* __restrict__ bv,
                                               __bf16* __restrict__ xb,
                                               __bf16* __restrict__ Wcat,
                                               __bf16* __restrict__ Wot,
                                               float* __restrict__ bcat) {
    const int bid = blockIdx.x;
    const int tid = threadIdx.x;
    if (bid < 8192) {                       // x -> bf16 (float4/lane)
        const long i = ((long)bid * 256 + tid) * 4;
        const float4 v = *(const float4*)(x + i);
        bf16x4 o;
        o[0] = (__bf16)v.x; o[1] = (__bf16)v.y; o[2] = (__bf16)v.z; o[3] = (__bf16)v.w;
        *(bf16x4*)(xb + i) = o;
    } else if (bid < 12288) {               // 4 weight transposes, 32x32 tiles
        __shared__ float tile[32][33];
        const int b2 = bid - 8192;
        const int w = b2 >> 10, t = b2 & 1023;
        const int r0 = (t >> 5) * 32, c0 = (t & 31) * 32;
        const float* src = (w == 0) ? Wq : (w == 1) ? Wk : (w == 2) ? Wv : Wo;
        __bf16* dst = (w < 3) ? (Wcat + (long)w * 1048576) : Wot;
        const int tx = tid & 31, ty = tid >> 5;
        #pragma unroll
        for (int j = ty; j < 32; j += 8)
            tile[j][tx] = src[(long)(r0 + j) * 1024 + (c0 + tx)];
        __syncthreads();
        #pragma unroll
        for (int j = ty; j < 32; j += 8)
            dst[(long)(c0 + j) * 1024 + (r0 + tx)] = (__bf16)tile[tx][j];
    } else {                                // bias concat [bq|bk|bv]
        const int i = (bid - 12288) * 256 + tid;
        if (i < 3072)
            bcat[i] = (i < 1024) ? bq[i] : ((i < 2048) ? bk[i - 1024] : bv[i - 2048]);
    }
}

// ---------- 256 x BN BT GEMM, BK=64, 2-phase single-barrier core -------------
// 8 waves (2M x 4N).  Per-wave output 128 x BN/4 = acc[8][NF], NF = BN/64.
// Per K-tile: { stage tile T+1 into buf^1 FIRST; compute(buf) compiler-
// scheduled; vmcnt(0); ONE s_barrier }.  Race-free per R12 proof.
// Swizzle (T2): 128B LDS rows, byte ^= ((row&7)<<4); inverse on global src.
// VTOUT (QKV): cols >= 2048 are V -- bounced through LDS (col-stride 528B)
//   and written COALESCED (16B) to Vt[b][dd][s].  Q/K cols direct-store.
// PVMODE: bz = batch*2 + ch; K = [ch*1024, min((by+1)*256, ch*1024+1024));
//   ch0/by<4 -> direct bf16 Cd; ch0/by>=4 -> M16 plane (rows-1024);
//   ch1 (by>=4) -> E1 plane (rows-1024).  merge2 sums planes.
template <typename Tout, int BN, bool CSKIP, bool PVMODE, bool SWZ, bool VTOUT>
__global__ __launch_bounds__(512, 1) void gemm2p(const __bf16* __restrict__ Ag,
                                                 const __bf16* __restrict__ Bg,
                                                 Tout* __restrict__ C0,
                                                 __bf16* __restrict__ M16,
                                                 __bf16* __restrict__ E1,
                                                 __bf16* __restrict__ Cd,
                                                 __bf16* __restrict__ Vt,
                                                 const float* __restrict__ bias,
                                                 int K, int lda, int ldb, int ldc,
                                                 int nbx, long sA, long sB, long sC) {
    constexpr int NF = BN / 64;
    constexpr int NB = BN / 64;
    int bx, by;
    const int bz = blockIdx.z;
    if (SWZ) {  // XCD-aware contiguous chunks (grid.x % 8 == 0)
        const int flat = blockIdx.x;
        const int w = (flat & 7) * ((int)gridDim.x >> 3) + (flat >> 3);
        bx = w % nbx; by = w / nbx;
    } else { bx = blockIdx.x; by = blockIdx.y; }
    if (CSKIP && bx * BN > by * 256 + 255) return;  // fully above causal diag

    const int m0 = by * 256, n0 = bx * BN;
    int kStart = 0, kEnd = K;
    const __bf16* A; const __bf16* B;
    Tout* C = nullptr;
    __bf16* Wout = nullptr;
    int rShift = 0;
    if (PVMODE) {
        const int b = bz >> 1, ch = bz & 1;
        kStart = ch << 10;
        kEnd = min((by + 1) * 256, kStart + 1024);
        if (kEnd <= kStart) return;          // chunk1 live only for by >= 4
        A = Ag + (long)b * sA;
        B = Bg + (long)b * sB;
        if (ch == 0) {
            if (by < 4) { rShift = 0;    Wout = Cd  + (long)b * sC; }
            else        { rShift = 1024; Wout = M16 + (long)b * 1048576; }
        } else          { rShift = 1024; Wout = E1  + (long)b * 1048576; }
    } else {
        A = Ag + (long)bz * sA;
        B = Bg + (long)bz * sB;
        C = C0 + (long)bz * sC;
    }
    const int NT = (kEnd - kStart) >> 6;   // BK=64 tiles (>= 4 always)

    // flat smem: As = [0,64K), Bs = [64K, 64K + BN*256); VTOUT bounce reuses it
    __shared__ __align__(16) char smem[65536 + BN * 256];

    const int tid = threadIdx.x;
    const int wid = tid >> 6, l = tid & 63;
    const int wm = wid >> 2, wn = wid & 3;          // wave grid 2(M) x 4(N)
    const int lr = l & 15, lu = l >> 4;

    // ---- staging source offsets (inverse-swizzled global cols, rule #21) ----
    int srcA[4], srcB[NB];
    #pragma unroll
    for (int i = 0; i < 4; ++i) {
        const int beta = i * 8192 + tid * 16;          // linear LDS byte
        const int r = beta >> 7;                       // row (128B rows)
        const int cb = (beta & 127) ^ ((r & 7) << 4);  // unswizzled col byte
        srcA[i] = (m0 + r) * lda + (cb >> 1);
    }
    #pragma unroll
    for (int i = 0; i < NB; ++i) {
        const int beta = i * 8192 + tid * 16;
        const int r = beta >> 7;
        const int cb = (beta & 127) ^ ((r & 7) << 4);
        srcB[i] = (n0 + r) * ldb + (cb >> 1);
    }
    auto stage = [&](int buf, int koff) {
        #pragma unroll
        for (int i = 0; i < 4; ++i)
            gload_lds16(A + srcA[i] + koff,
                        smem + buf * 32768 + i * 8192 + wid * 1024);
        #pragma unroll
        for (int j = 0; j < NB; ++j)
            gload_lds16(B + srcB[j] + koff,
                        smem + 65536 + buf * (BN * 128) + j * 8192 + wid * 1024);
    };

    // ---- swizzled fragment read offsets (elements), lane constants ----
    const int xo  = (lr & 7) << 4;                       // row-derived XOR
    const int c0e = ((lu << 4) ^ xo) >> 1;               // kk=0 col elems
    const int c1e = ((64 + (lu << 4)) ^ xo) >> 1;        // kk=1 col elems
    const int aLo = (wm * 64 + lr) * 64;                 // rows wm*64 + m*16
    const int aHi = (128 + wm * 64 + lr) * 64;           // rows 128 + wm*64 ..
    const int bBase = (wn * (BN / 4) + lr) * 64;

    f32x4 acc[8][NF] = {};

    // ---- prologue: stage tile 0, publish ----
    stage(0, kStart);
    asm volatile("s_waitcnt vmcnt(0)" ::: "memory");
    BAR();

    for (int T = 0; T < NT; ++T) {
        const int c = T & 1;
        const bool more = (T + 1 < NT);
        if (more) stage(c ^ 1, kStart + (T + 1) * 64);   // issue loads FIRST

        // compute on buf c -- compiler schedules ds_read || MFMA freely
        const __bf16* Ab = (const __bf16*)(smem + c * 32768);
        const __bf16* Bb = (const __bf16*)(smem + 65536 + c * (BN * 128));
        #pragma unroll
        for (int kk = 0; kk < 2; ++kk) {
            const int ce = kk ? c1e : c0e;
            bf16x8 aR[8], bR[NF];
            #pragma unroll
            for (int m = 0; m < 4; ++m) {
                aR[m]     = *(const bf16x8*)(Ab + aLo + m * 1024 + ce);
                aR[4 + m] = *(const bf16x8*)(Ab + aHi + m * 1024 + ce);
            }
            #pragma unroll
            for (int n = 0; n < NF; ++n)
                bR[n] = *(const bf16x8*)(Bb + bBase + n * 1024 + ce);
            #pragma unroll
            for (int m = 0; m < 8; ++m)
                #pragma unroll
                for (int n = 0; n < NF; ++n)
                    acc[m][n] = __builtin_amdgcn_mfma_f32_16x16x32_bf16(
                        aR[m], bR[n], acc[m][n], 0, 0, 0);
        }

        if (more) {
            asm volatile("s_waitcnt vmcnt(0)" ::: "memory");  // buf c^1 landed
            BAR();                                            // publish
        }
    }

    // epilogue: C/D layout col = lane&15, row = (lane>>4)*4 + reg [m89-verified]
    // acc index mi -> C row m0 + (mi>>2)*128 + wm*64 + (mi&3)*16 + rb
    const int rb = lu * 4, cl = lr;

    // (a) direct stores (all cols for non-VTOUT; Q/K cols for VTOUT)
    #pragma unroll
    for (int n = 0; n < NF; ++n) {
        const int col = n0 + wn * (BN / 4) + n * 16 + cl;
        if (VTOUT && col >= 2048) continue;
        const float bvv = bias ? bias[col] : 0.f;
        #pragma unroll
        for (int mi = 0; mi < 8; ++mi) {
            const int row = m0 + (mi >> 2) * 128 + wm * 64 + (mi & 3) * 16 + rb;
            #pragma unroll
            for (int r = 0; r < 4; ++r) {
                const float v = acc[mi][n][r] + bvv;
                if constexpr (PVMODE)
                    Wout[(long)(row + r - rShift) * ldc + col] = (__bf16)v;
                else
                    C[(long)(row + r) * ldc + col] = (Tout)v;
            }
        }
    }

    // (b-e) V columns: LDS bounce -> coalesced 16B stores to Vt[b][dd][s]
    if constexpr (VTOUT) {
        const bool hasV = (n0 + BN > 2048);     // block-uniform
        if (hasV) {
            __syncthreads();                    // all waves done with As/Bs
            // (c) ds_write_b64 V values into [lcol][row] image, stride 528B
            #pragma unroll
            for (int n = 0; n < NF; ++n) {
                const int col = n0 + wn * (BN / 4) + n * 16 + cl;
                if (col < 2048) continue;
                const int lcol = wn * (BN / 4) + n * 16 + cl;
                const float bvv = bias ? bias[col] : 0.f;
                #pragma unroll
                for (int mi = 0; mi < 8; ++mi) {
                    const int rl = (mi >> 2) * 128 + wm * 64 + (mi & 3) * 16 + rb;
                    bf16x4 o;
                    #pragma unroll
                    for (int r = 0; r < 4; ++r) o[r] = (__bf16)(acc[mi][n][r] + bvv);
                    *(bf16x4*)(smem + lcol * 528 + rl * 2) = o;
                }
            }
            __syncthreads();
            // (e) coalesced readout: 16B per store, 8 s-positions per dd
            const int vStart = (n0 >= 2048) ? 0 : (2048 - n0);
            const int nV = BN - vStart;
            const int bb = m0 >> 11, s0 = m0 & 2047;
            for (int t = tid; t < nV * 32; t += 512) {
                const int ddl = vStart + (t >> 5);
                const int sl = (t & 31) * 8;
                const bf16x8 v = *(const bf16x8*)(smem + ddl * 528 + sl * 2);
                *(bf16x8*)(Vt + (long)bb * 2097152 +
                           (long)(n0 + ddl - 2048) * 2048 + s0 + sl) = v;
            }
        }
    }
}

// ------ merge PV partials (rows 1024..2047): ctxb = bf16(M16 + E1) -----------
__global__ __launch_bounds__(256) void merge2(const __bf16* __restrict__ M16,
                                              const __bf16* __restrict__ E1,
                                              __bf16* __restrict__ out) {
    const long i = ((long)blockIdx.x * 256 + threadIdx.x) * 8;  // [0, B*1048576)
    const long b = i >> 20;
    const long j = i & 1048575;
    const bf16x8 a = *(const bf16x8*)(M16 + b * 1048576 + j);
    const bf16x8 c = *(const bf16x8*)(E1 + b * 1048576 + j);
    bf16x8 o;
    #pragma unroll
    for (int t = 0; t < 8; ++t) o[t] = (__bf16)((float)a[t] + (float)c[t]);
    *(bf16x8*)(out + b * 2097152 + 1048576 + j) = o;
}

// ---------------- causal softmax row kernel (16B/lane, bounded I/O) ----------
__global__ __launch_bounds__(256) void softmax_causal(const __bf16* __restrict__ scores,
                                                      __bf16* __restrict__ P, float scale) {
    const int q = blockIdx.x;
    const long b = blockIdx.y;
    const __bf16* srow = scores + (b * SDIM + q) * (long)SDIM;
    __bf16* prow = P + (b * SDIM + q) * (long)SDIM;
    const int n = q + 1;
    const int kBound = ((q >> 8) + 1) << 8;    // PV reads P cols < kBound only
    const int tid = threadIdx.x;
    const int k0 = tid * 8;
    __shared__ float red[8];

    float vals[8];
    float mx = -1e30f;
    if (k0 < n) {
        const bf16x8 v = *(const bf16x8*)(srow + k0);
        #pragma unroll
        for (int i = 0; i < 8; ++i) {
            const float s = (k0 + i < n) ? (float)v[i] * scale : -1e30f;
            vals[i] = s;
            mx = fmaxf(mx, s);
        }
    } else {
        #pragma unroll
        for (int i = 0; i < 8; ++i) vals[i] = -1e30f;
    }
    #pragma unroll
    for (int o = 32; o > 0; o >>= 1) mx = fmaxf(mx, __shfl_xor(mx, o));
    if ((tid & 63) == 0) red[tid >> 6] = mx;
    __syncthreads();
    mx = fmaxf(fmaxf(red[0], red[1]), fmaxf(red[2], red[3]));

    float p[8];
    float sum = 0.f;
    #pragma unroll
    for (int i = 0; i < 8; ++i) {
        p[i] = __expf(vals[i] - mx);
        sum += p[i];
    }
    #pragma unroll
    for (int o = 32; o > 0; o >>= 1) sum += __shfl_xor(sum, o);
    if ((tid & 63) == 0) red[4 + (tid >> 6)] = sum;
    __syncthreads();
    sum = red[4] + red[5] + red[6] + red[7];

    if (k0 < kBound) {                     // cols >= kBound never read by PV
        const float inv = 1.f / sum;
        bf16x8 o;
        #pragma unroll
        for (int i = 0; i < 8; ++i)
            o[i] = (__bf16)((k0 + i < n) ? p[i] * inv : 0.f);
        *(bf16x8*)(prow + k0) = o;
    }
}

extern "C" void kernel_launch(void* const* d_in, const int* in_sizes, int n_in,
                              void* d_out, int out_size, void* d_ws, size_t ws_size,
                              hipStream_t stream) {
    const float* x  = (const float*)d_in[0];
    // d_in[1] = mask (tril ones) -- causality enforced by index, unused.
    const float* Wq = (const float*)d_in[2];
    const float* bq = (const float*)d_in[3];
    const float* Wk = (const float*)d_in[4];
    const float* bk = (const float*)d_in[5];
    const float* Wv = (const float*)d_in[6];
    const float* bv = (const float*)d_in[7];
    const float* Wo = (const float*)d_in[8];
    const float* bo = (const float*)d_in[9];
    float* out = (float*)d_out;

    char* ws = (char*)d_ws;
    const long XE = (long)BATCH * SDIM * BDIM;    // 8,388,608
    __bf16* xb    = (__bf16*)(ws);                // 16 MiB, dead after QKV
    __bf16* Wcat  = (__bf16*)(ws + 16777216);     // 6 MiB
    __bf16* Wot   = (__bf16*)(ws + 23068672);     // 2 MiB
    float*  bcat  = (float*)(ws + 25165824);      // 12 KiB
    __bf16* QKVb  = (__bf16*)(ws + 25178112);     // 48 MiB (8192 x 3072; V cols unused)
    __bf16* Vtb   = (__bf16*)(ws + 75509760);     // 16 MiB (B x [1024][2048])
    __bf16* Sc    = (__bf16*)(ws + 92286976);     // 32 MiB, dead after softmax
    __bf16* Pb    = (__bf16*)(ws + 25178112);     // alias QKVb[0..32M)
    __bf16* M16   = (__bf16*)(ws + 92286976);     // 8 MiB, alias Sc
    __bf16* E1    = (__bf16*)(ws + 100675584);    // 8 MiB, alias Sc+8M
    __bf16* ctxb  = (__bf16*)(ws + 58732544);     // 16 MiB, alias QKVb[32M..48M)

    const long SD  = (long)SDIM * BDIM;           // 2,097,152
    const long SS  = (long)SDIM * SDIM;           // 4,194,304
    const long SQ3 = (long)SDIM * 3 * BDIM;       // 6,291,456

    // fused pre-pass: cvt x (8192 blocks) + 4 W^T (4096) + bias concat (12)
    prepass<<<dim3(12300), 256, 0, stream>>>(x, Wq, Wk, Wv, Wo, bq, bk, bv,
                                             xb, Wcat, Wot, bcat);

    // QKV: Q,K cols -> QKVb; V cols -> Vtb transposed via LDS bounce (BN=192)
    gemm2p<__bf16, 192, false, false, true, true><<<dim3(512, 1, 1), 512, 0, stream>>>(
        xb, Wcat, QKVb, nullptr, nullptr, nullptr, Vtb, bcat,
        BDIM, BDIM, BDIM, 3072, 16, 0, 0, 0);
    // scores = Q @ K^T per batch (causal tile skip; 144 live blocks)
    gemm2p<__bf16, 256, true, false, false, false><<<dim3(8, 8, BATCH), 512, 0, stream>>>(
        QKVb, QKVb + 1024, Sc, nullptr, nullptr, nullptr, nullptr, nullptr,
        BDIM, 3072, 3072, SDIM, 8, SQ3, SQ3, SS);
    // causal softmax (scale = 1/32)
    softmax_causal<<<dim3(SDIM, BATCH), 256, 0, stream>>>(Sc, Pb, 0.03125f);
    // ctx = P @ V, 2 K-chunks @1024 (192 live blocks); bf16 partials:
    // ch0/by<4 -> ctxb direct; ch0/by>=4 -> M16; ch1 -> E1
    gemm2p<__bf16, 256, false, true, false, false><<<dim3(4, 8, 2 * BATCH), 512, 0, stream>>>(
        Pb, Vtb, nullptr, M16, E1, ctxb, nullptr, nullptr,
        SDIM, SDIM, SDIM, BDIM, 4, SS, SD, SD);
    // merge partial planes (rows 1024..2047) -> bf16 ctx
    merge2<<<dim3((unsigned)(BATCH * 1048576 / 8 / 256)), 256, 0, stream>>>(
        M16, E1, ctxb);
    // out = ctx @ Wo + bo (BN=128: 256 blocks = full machine, swz)
    gemm2p<float, 128, false, false, true, false><<<dim3(256, 1, 1), 512, 0, stream>>>(
        ctxb, Wot, out, nullptr, nullptr, nullptr, nullptr, bo,
        BDIM, BDIM, BDIM, BDIM, 8, 0, 0, 0);
}